// Round 4
// baseline (289.506 us; speedup 1.0000x reference)
//
#include <hip/hip_runtime.h>

// MFB fused non-local block, round 12.
// r11 post-mortem: pipelined 128^2 gemm helped conv/out (-23us) but s itself
// regressed (55.8->62.5, co-residency 26->19%). s moves 2.7 MB/CU through the
// vmem port (2.1 MB L2->LDS staging at 28 FLOP/byte + 0.6 MB HBM). Round 12:
// s gets a 256x256 tile (512 thr, 8 waves, acc[8][4], BK=32, 3-buf 2-deep
// vmcnt(4) pipeline) -> staged bytes/CU 2.1 -> 1.05 MB, same 8 waves/CU.
// conv/out/av unchanged.

#define N_ 4096
#define C_ 512
#define IC_ 256
#define B_ 4

typedef __bf16 bf16_t;
typedef __bf16 bf16x8 __attribute__((ext_vector_type(8)));
typedef __bf16 bf16x4 __attribute__((ext_vector_type(4)));
typedef float f32x4 __attribute__((ext_vector_type(4)));

#define GLD(g, l) __builtin_amdgcn_global_load_lds(                              \
    (const __attribute__((address_space(1))) void*)(g),                          \
    (__attribute__((address_space(3))) void*)(l), 16, 0, 0)

// ---------------------------------------------------------------------------
// C[128x128] += A[m0.., K] * Bt[n0.., K]^T, bf16 in, fp32 acc. K mult of 64.
// 256 threads = 4 waves; wave (wr,wc) owns 64x64; acc[4][4] of f32x4.
// C/D layout (m89/m91): (i,j,reg) -> row wr+i*16+q*4+reg, col wc+j*16+l15.
// LDS: XOR-swizzled 64-elem rows; slot (row, c) holds global chunk c^(row&7).
// 2-buffer pipeline, smem = [2][lsA 8192 | lsB 8192] = 32768 elems (64 KB).
// ---------------------------------------------------------------------------
__device__ __forceinline__ void gemm_bt_128x128(
    const bf16_t* __restrict__ A, int lda,
    const bf16_t* __restrict__ Bt, int ldb,
    int K, int m0, int n0,
    bf16_t* smem, f32x4 acc[4][4])
{
    const int tid  = threadIdx.x;
    const int wave = tid >> 6, lane = tid & 63;
    const int wr = (wave >> 1) * 64, wc = (wave & 1) * 64;
    const int q = lane >> 4, l15 = lane & 15;
    const int srow = lane >> 3;                         // 0..7
    const int scol = (((lane & 7) ^ (srow & 7)) * 8);   // swizzled 8-elem chunk
    const int swz  = l15 & 7;

#define GB_STAGE(bi, kt)                                                        \
    do {                                                                        \
        bf16_t* lA = smem + (bi) * 16384;                                       \
        bf16_t* lB = lA + 8192;                                                 \
        _Pragma("unroll")                                                       \
        for (int c = 0; c < 4; ++c) {                                           \
            const int ch = wave * 4 + c;                                        \
            GLD(A  + (size_t)(m0 + ch * 8 + srow) * lda + (kt) + scol,          \
                lA + ch * 512);                                                 \
            GLD(Bt + (size_t)(n0 + ch * 8 + srow) * ldb + (kt) + scol,          \
                lB + ch * 512);                                                 \
        }                                                                       \
    } while (0)

    GB_STAGE(0, 0);
    asm volatile("s_waitcnt vmcnt(0)" ::: "memory");
    __builtin_amdgcn_s_barrier();
    asm volatile("" ::: "memory");

    const int nt = K / 64;
    for (int t = 0; t < nt; ++t) {
        const int cur = t & 1;
        if (t + 1 < nt) GB_STAGE(cur ^ 1, (t + 1) * 64);   // prefetch, in flight
        const bf16_t* lsA = smem + cur * 16384;
        const bf16_t* lsB = lsA + 8192;
#pragma unroll
        for (int ks = 0; ks < 2; ++ks) {
            bf16x8 af[4], bfr[4];
            const int co = ((ks * 4 + q) ^ swz) * 8;
#pragma unroll
            for (int i = 0; i < 4; ++i) {
                af[i]  = *(const bf16x8*)&lsA[(wr + i * 16 + l15) * 64 + co];
                bfr[i] = *(const bf16x8*)&lsB[(wc + i * 16 + l15) * 64 + co];
            }
#pragma unroll
            for (int i = 0; i < 4; ++i)
#pragma unroll
                for (int j = 0; j < 4; ++j)
                    acc[i][j] = __builtin_amdgcn_mfma_f32_16x16x32_bf16(
                        af[i], bfr[j], acc[i][j], 0, 0, 0);
        }
        // next tile's loads (issued above) land under the compute we just did
        asm volatile("s_waitcnt vmcnt(0)" ::: "memory");
        __builtin_amdgcn_s_barrier();
        asm volatile("" ::: "memory");
    }
#undef GB_STAGE
}

#define ACC_ZERO(acc)                                                           \
    _Pragma("unroll") for (int i = 0; i < 4; ++i)                               \
    _Pragma("unroll") for (int j = 0; j < 4; ++j)                               \
        acc[i][j] = f32x4{0.f, 0.f, 0.f, 0.f};

// ---- prep: castw3 (blocks 0..1535) | wf compose (1536..2047) | zero rowsum
__global__ __launch_bounds__(256) void prep_k(
    const float* __restrict__ wk, const float* __restrict__ wv,
    const float* __restrict__ wq,
    const float* __restrict__ wwg, const float* __restrict__ wout,
    const float* __restrict__ bout,
    const float* __restrict__ g1, const float* __restrict__ b1,
    const float* __restrict__ m1, const float* __restrict__ v1,
    const float* __restrict__ g2, const float* __restrict__ b2,
    const float* __restrict__ m2, const float* __restrict__ v2,
    bf16_t* __restrict__ Wb3, bf16_t* __restrict__ Wfb,
    float* __restrict__ bfv, float* __restrict__ rowsum)
{
    const int bid = blockIdx.x;
    __shared__ float ws[256];
    __shared__ float red[4];

    if (bid < 1536) {                 // cast wk|wv|wq to bf16
        const int i = bid * 256 + threadIdx.x;
        float v;
        if      (i < 131072) v = wk[i];
        else if (i < 262144) v = wv[i - 131072];
        else                 v = wq[i - 262144];
        Wb3[i] = (bf16_t)v;
    } else if (bid < 2048) {          // Wf = diag(s2) wout diag(s1) wwg + bias
        const int o = bid - 1536;     // 0..511
        const int j = threadIdx.x;    // 0..255
        const float s1 = g1[j] * rsqrtf(v1[j] + 1e-5f);
        const float wo = wout[o * 256 + j];
        ws[j] = wo * s1;
        float bp = wo * (b1[j] - m1[j] * s1);
#pragma unroll
        for (int off = 32; off > 0; off >>= 1) bp += __shfl_down(bp, off);
        if ((j & 63) == 0) red[j >> 6] = bp;
        __syncthreads();

        float acc = 0.f;
#pragma unroll 4
        for (int ic = 0; ic < 256; ++ic)
            acc += ws[ic] * wwg[ic * 256 + j];

        const float s2 = g2[o] * rsqrtf(v2[o] + 1e-5f);
        Wfb[o * 256 + j] = (bf16_t)(acc * s2);
        if (j == 0)
            bfv[o] = s2 * (red[0] + red[1] + red[2] + red[3] + bout[o])
                     - s2 * m2[o] + b2[o];
    } else {                          // zero rowsum[b][n] (16384 floats)
        rowsum[(bid - 2048) * 256 + threadIdx.x] = 0.f;
    }
}

// --------------------------------------------- xA [b,c,n] -> xAt [b,n,c] bf16
__global__ __launch_bounds__(256) void txa_k(
    const float* __restrict__ xA, bf16_t* __restrict__ xAt)
{
    __shared__ float t[32][33];
    const int b = blockIdx.z;
    const int n0 = blockIdx.x * 32, c0 = blockIdx.y * 32;
    const int tx = threadIdx.x, ty = threadIdx.y;
    const float* X = xA + (size_t)b * C_ * N_;
    bf16_t* Y = xAt + (size_t)b * N_ * C_;
#pragma unroll
    for (int r = 0; r < 4; ++r)
        t[ty + r * 8][tx] = X[(size_t)(c0 + ty + r * 8) * N_ + n0 + tx];
    __syncthreads();
#pragma unroll
    for (int r = 0; r < 4; ++r)
        Y[(size_t)(n0 + ty + r * 8) * C_ + c0 + tx] = (bf16_t)t[tx][ty + r * 8];
}

// ------------------------------------------ conv KVQ: W[o,c] * xAt[n,c]^T
__global__ __launch_bounds__(256) void conv_mfma_k(
    const bf16_t* __restrict__ Wb3,
    const float* __restrict__ bk, const float* __restrict__ bv,
    const float* __restrict__ bq, const bf16_t* __restrict__ xAt,
    bf16_t* __restrict__ Kb, bf16_t* __restrict__ Vt, bf16_t* __restrict__ Qt)
{
    __shared__ bf16_t smem[32768];
    const int which = blockIdx.z % 3, b = blockIdx.z / 3;
    const bf16_t* A = Wb3 + which * 131072;
    const float* bias = (which == 0) ? bk : (which == 1 ? bv : bq);
    const bf16_t* Bt = xAt + (size_t)b * N_ * C_;
    const int n0 = blockIdx.x * 128, m0 = blockIdx.y * 128;

    f32x4 acc[4][4];
    ACC_ZERO(acc);
    gemm_bt_128x128(A, C_, Bt, C_, C_, m0, n0, smem, acc);

    const int lane = threadIdx.x & 63, wave = threadIdx.x >> 6;
    const int q = lane >> 4, l15 = lane & 15;
    const int wr = (wave >> 1) * 64, wc = (wave & 1) * 64;

    if (which == 0) {                     // K: [c, n], n contiguous
        bf16_t* Y = Kb + (size_t)b * IC_ * N_;
#pragma unroll
        for (int i = 0; i < 4; ++i)
#pragma unroll
            for (int r = 0; r < 4; ++r) {
                const int o = m0 + wr + i * 16 + q * 4 + r;
                const float bo = bias[o];
#pragma unroll
                for (int j = 0; j < 4; ++j)
                    Y[(size_t)o * N_ + n0 + wc + j * 16 + l15] =
                        (bf16_t)(acc[i][j][r] + bo);
            }
    } else {                              // V/Q: [n, c], c contiguous
        bf16_t* Y = ((which == 1) ? Vt : Qt) + (size_t)b * N_ * IC_;
#pragma unroll
        for (int i = 0; i < 4; ++i) {
            const int ob = m0 + wr + i * 16 + q * 4;
            float bo[4];
#pragma unroll
            for (int r = 0; r < 4; ++r) bo[r] = bias[ob + r];
#pragma unroll
            for (int j = 0; j < 4; ++j) {
                const int n = n0 + wc + j * 16 + l15;
                bf16x4 v4;
#pragma unroll
                for (int r = 0; r < 4; ++r) v4[r] = (bf16_t)(acc[i][j][r] + bo[r]);
                *(bf16x4*)&Y[(size_t)n * IC_ + ob] = v4;
            }
        }
    }
}

// ---- S^T GEMM (batched), round 12: 256x256 tile, 512 threads = 8 waves
//      (2m x 4n, wave tile 128m x 64n, acc[8][4]). BK=32, 3-buffer 2-deep
//      counted-vmcnt pipeline. D[m,n] = Qt[m,:].Vt[n,:]; Pt[m,n] = exp(D)
//      bf16; rowsum[n] += column sums. Epilogue: two 128-col phases through
//      a stride-136 LDS stage -> b128 stores.
//      LDS swizzle (BK=32, 64B rows, 4 chunks/row): slot c of row r holds
//      global chunk c ^ sw(r), sw(r) = (r&3)^((r>>2)&3) -> 2-way max on reads.
__global__ __launch_bounds__(512, 2) void s_mfma_t_k(
    const bf16_t* __restrict__ Qt, const bf16_t* __restrict__ Vt,
    bf16_t* __restrict__ Pt, float* __restrict__ rowsum)
{
    __shared__ bf16_t smem[49152];        // 3 x (A 8192 | B 8192) = 96 KB
    const int b  = blockIdx.z;
    const int n0 = blockIdx.x * 256;      // cols (n)
    const int m0 = blockIdx.y * 256;      // rows (m)
    const size_t NIC = (size_t)N_ * IC_;
    const bf16_t* Qb = Qt + (size_t)b * NIC;
    const bf16_t* Vb = Vt + (size_t)b * NIC;
    bf16_t* Pb = Pt + (size_t)b * N_ * N_;
    float* rs = rowsum + b * N_;

    const int tid  = threadIdx.x;         // 0..511
    const int wave = tid >> 6, lane = tid & 63;
    const int wr = wave >> 2;             // 0..1: m half (128 rows)
    const int wn = wave & 3;              // 0..3: n quarter (64 cols)
    const int q = lane >> 4, l15 = lane & 15;
    // staging: chunk = 1024B = 16 rows x 32 elems; lane: row lane>>2, slot lane&3
    const int lr  = lane >> 2;
    const int swl = ((lane >> 2) & 3) ^ ((lane >> 4) & 3);
    const int sc8 = ((lane & 3) ^ swl) * 8;
    // fragment read: row-local swizzle
    const int swr = (l15 & 3) ^ ((l15 >> 2) & 3);
    const int co  = (q ^ swr) * 8;

    f32x4 acc[8][4];
#pragma unroll
    for (int i = 0; i < 8; ++i)
#pragma unroll
        for (int j = 0; j < 4; ++j) acc[i][j] = f32x4{0.f, 0.f, 0.f, 0.f};

    // per wave per tile: 2 A-chunks + 2 B-chunks (16 chunks each over 8 waves)
#define S_STAGE(buf, kt)                                                        \
    do {                                                                        \
        _Pragma("unroll")                                                       \
        for (int c = 0; c < 2; ++c) {                                           \
            const int ch = wave * 2 + c;                                        \
            const int gr = ch * 16 + lr;                                        \
            GLD(Qb + (size_t)(m0 + gr) * IC_ + (kt) + sc8, (buf) + ch * 512);   \
            GLD(Vb + (size_t)(n0 + gr) * IC_ + (kt) + sc8,                      \
                (buf) + 8192 + ch * 512);                                       \
        }                                                                       \
    } while (0)

    const int NT = IC_ / 32;              // 8 K-tiles
    S_STAGE(smem, 0);                     // 2 tiles in flight
    S_STAGE(smem + 16384, 32);

    int bc = 0, bs = 2;
    for (int t = 0; t < NT; ++t) {
        if (t + 1 < NT) {
            asm volatile("s_waitcnt vmcnt(4)" ::: "memory");   // tile t landed
        } else {
            asm volatile("s_waitcnt vmcnt(0)" ::: "memory");
        }
        __builtin_amdgcn_s_barrier();
        asm volatile("" ::: "memory");
        if (t + 2 < NT) S_STAGE(smem + bs * 16384, (t + 2) * 32);

        const bf16_t* lsA = smem + bc * 16384;
        const bf16_t* lsB = lsA + 8192;
        bf16x8 af[8], bf[4];
#pragma unroll
        for (int i = 0; i < 8; ++i)
            af[i] = *(const bf16x8*)&lsA[(wr * 128 + i * 16 + l15) * 32 + co];
#pragma unroll
        for (int j = 0; j < 4; ++j)
            bf[j] = *(const bf16x8*)&lsB[(wn * 64 + j * 16 + l15) * 32 + co];
#pragma unroll
        for (int i = 0; i < 8; ++i)
#pragma unroll
            for (int j = 0; j < 4; ++j)
                acc[i][j] = __builtin_amdgcn_mfma_f32_16x16x32_bf16(
                    af[i], bf[j], acc[i][j], 0, 0, 0);
        bc = (bc == 2) ? 0 : bc + 1;
        bs = (bs == 2) ? 0 : bs + 1;
    }
#undef S_STAGE

    // ---- epilogue: exp + column sums + Pt store, two 128-col phases.
    // (safe to reuse smem: all waves' final ds_reads completed before the
    //  last barrier since their MFMAs consumed them)
#pragma unroll
    for (int h = 0; h < 2; ++h) {
        if ((wn >> 1) == h) {
#pragma unroll
            for (int j = 0; j < 4; ++j) {
                float cs = 0.f;
#pragma unroll
                for (int i = 0; i < 8; ++i)
#pragma unroll
                    for (int r = 0; r < 4; ++r) {
                        const float e = __expf(acc[i][j][r]);
                        cs += e;
                        smem[(wr * 128 + i * 16 + q * 4 + r) * 136 +
                             (wn & 1) * 64 + j * 16 + l15] = (bf16_t)e;
                    }
                cs += __shfl_xor(cs, 16);
                cs += __shfl_xor(cs, 32);
                if (q == 0) atomicAdd(&rs[n0 + wn * 64 + j * 16 + l15], cs);
            }
        }
        __syncthreads();
        const int rr0 = tid >> 4;         // 0..31
        const int cc  = (tid & 15) * 8;   // 0..120
#pragma unroll
        for (int pp = 0; pp < 8; ++pp) {
            const int rr = rr0 + pp * 32;
            const bf16x8 v = *(const bf16x8*)&smem[rr * 136 + cc];
            *(bf16x8*)&Pb[(size_t)(m0 + rr) * N_ + n0 + h * 128 + cc] = v;
        }
        __syncthreads();
    }
}

// --------------- K'[b][c,n] = K[b][c,n] / rowsum[b][n], in-place (batched)
__global__ __launch_bounds__(256) void kscale_k(
    bf16_t* __restrict__ Kb, const float* __restrict__ rowsum)
{
    const size_t i8 = ((size_t)blockIdx.x * 256 + threadIdx.x) * 8;  // 2048 blocks
    const int n = (int)(i8 & (N_ - 1));
    const int b = (int)(i8 >> 20);                 // IC_*N_ = 2^20
    const float* rs = rowsum + b * N_;
    bf16x8 v = *(bf16x8*)&Kb[i8];
    const f32x4 r0 = *(const f32x4*)&rs[n];
    const f32x4 r1 = *(const f32x4*)&rs[n + 4];
#pragma unroll
    for (int k = 0; k < 4; ++k) {
        v[k]     = (bf16_t)((float)v[k]     / r0[k]);
        v[4 + k] = (bf16_t)((float)v[4 + k] / r1[k]);
    }
    *(bf16x8*)&Kb[i8] = v;
}

// ---- av GEMM (r10 structure, unchanged): 128m x 128c tile, grid (32,2,4) =
//      256 blocks. 3-buffer 2-deep pipeline with counted vmcnt(8).
__global__ __launch_bounds__(256) void av_mfma_k(
    const bf16_t* __restrict__ Pt, const bf16_t* __restrict__ Kb,
    bf16_t* __restrict__ avTb)
{
    // 3 buffers x (lsA 128x64 | lsB 128x64) = 3 x 32 KB = 96 KB.
    __shared__ bf16_t smem[3 * 16384];
    const int b  = blockIdx.z;
    const int m0 = blockIdx.x * 128;
    const int c0 = blockIdx.y * 128;
    const size_t NIC = (size_t)N_ * IC_;
    const bf16_t* Pb  = Pt + (size_t)b * N_ * N_ + (size_t)m0 * N_;
    const bf16_t* Kbb = Kb + (size_t)b * NIC + (size_t)c0 * N_;

    const int tid = threadIdx.x;
    const int wave = tid >> 6, lane = tid & 63;
    const int wr = (wave >> 1) * 64, wc = (wave & 1) * 64;
    const int q = lane >> 4, l15 = lane & 15;
    const int srow = lane >> 3;
    const int scol = (((lane & 7) ^ (srow & 7)) * 8);
    const int swz  = l15 & 7;

    f32x4 acc[4][4];
    ACC_ZERO(acc);

    // 8 GLDs per wave per tile: 4 A-chunks + 4 B-chunks (8 rows x 64 each).
#define AV_STAGE(buf, kt)                                                       \
    do {                                                                        \
        _Pragma("unroll")                                                       \
        for (int c = 0; c < 4; ++c) {                                           \
            const int ch = wave * 4 + c;                                        \
            GLD(Pb  + (size_t)(ch * 8 + srow) * N_ + (kt) + scol,               \
                (buf) + ch * 512);                                              \
            GLD(Kbb + (size_t)(ch * 8 + srow) * N_ + (kt) + scol,               \
                (buf) + 8192 + ch * 512);                                       \
        }                                                                       \
    } while (0)

    const int NT = N_ / 64;               // 64 K-tiles
    AV_STAGE(smem, 0);                    // prologue: 2 tiles in flight
    AV_STAGE(smem + 16384, 64);

    int bi_c = 0;                         // buffer holding tile t
    int bi_s = 2;                         // buffer to stage tile t+2 into
    for (int t = 0; t < NT; ++t) {
        if (t + 2 < NT) {
            // own tile-t loads done (8 newer, tile t+1, stay in flight)
            asm volatile("s_waitcnt vmcnt(8)" ::: "memory");
            __builtin_amdgcn_s_barrier();
            asm volatile("" ::: "memory");
            AV_STAGE(smem + bi_s * 16384, (t + 2) * 64);
        } else {
            asm volatile("s_waitcnt vmcnt(0)" ::: "memory");
            __builtin_amdgcn_s_barrier();
            asm volatile("" ::: "memory");
        }
        const bf16_t* lsA = smem + bi_c * 16384;
        const bf16_t* lsB = lsA + 8192;
#pragma unroll
        for (int ks = 0; ks < 2; ++ks) {
            const int co2 = ((ks * 4 + q) ^ swz) * 8;
            bf16x8 af[4], bfr[4];
#pragma unroll
            for (int i = 0; i < 4; ++i) {
                af[i]  = *(const bf16x8*)&lsA[(wr + i * 16 + l15) * 64 + co2];
                bfr[i] = *(const bf16x8*)&lsB[(wc + i * 16 + l15) * 64 + co2];
            }
#pragma unroll
            for (int i = 0; i < 4; ++i)
#pragma unroll
                for (int j = 0; j < 4; ++j)
                    acc[i][j] = __builtin_amdgcn_mfma_f32_16x16x32_bf16(
                        af[i], bfr[j], acc[i][j], 0, 0, 0);
        }
        bi_c = (bi_c == 2) ? 0 : bi_c + 1;
        bi_s = (bi_s == 2) ? 0 : bi_s + 1;
    }
#undef AV_STAGE
    __syncthreads();                      // all ds_reads of last tile done

    // epilogue: stage 128x128 bf16 (stride 136 elems = 272 B, 16B-aligned)
#pragma unroll
    for (int i = 0; i < 4; ++i)
#pragma unroll
        for (int j = 0; j < 4; ++j)
#pragma unroll
            for (int r = 0; r < 4; ++r)
                smem[(wr + i * 16 + q * 4 + r) * 136 + wc + j * 16 + l15] =
                    (bf16_t)acc[i][j][r];
    __syncthreads();

    bf16_t* Y = avTb + (size_t)b * NIC + (size_t)m0 * IC_ + c0;
    const int rr = tid >> 4;              // 0..15
    const int cc = (tid & 15) * 8;        // 0..120
#pragma unroll
    for (int p = 0; p < 8; ++p) {
        const int mm = rr + p * 16;
        const bf16x8 v = *(const bf16x8*)&smem[mm * 136 + cc];
        *(bf16x8*)&Y[(size_t)mm * IC_ + cc] = v;
    }
}

// ------------ final: out = relu( Wf . avT + bfv + xA ), fp32 out (batched)
__global__ __launch_bounds__(256) void out_mfma_k(
    const bf16_t* __restrict__ Wfb, const float* __restrict__ bfv,
    const bf16_t* __restrict__ avTb,
    const float* __restrict__ xA, float* __restrict__ out)
{
    __shared__ bf16_t smem[32768];
    const int b = blockIdx.z;
    const bf16_t* Bt = avTb + (size_t)b * N_ * IC_;
    const int n0 = blockIdx.x * 128, o0 = blockIdx.y * 128;

    f32x4 acc[4][4];
    ACC_ZERO(acc);
    gemm_bt_128x128(Wfb, IC_, Bt, IC_, IC_, o0, n0, smem, acc);

    const int lane = threadIdx.x & 63, wave = threadIdx.x >> 6;
    const int q = lane >> 4, l15 = lane & 15;
    const int wr = (wave >> 1) * 64, wc = (wave & 1) * 64;

#pragma unroll
    for (int i = 0; i < 4; ++i)
#pragma unroll
        for (int r = 0; r < 4; ++r) {
            const int o = o0 + wr + i * 16 + q * 4 + r;
            const float bo = bfv[o];
#pragma unroll
            for (int j = 0; j < 4; ++j) {
                const int n = n0 + wc + j * 16 + l15;
                const size_t idx = ((size_t)b * C_ + o) * N_ + n;
                out[idx] = fmaxf(acc[i][j][r] + bo + xA[idx], 0.f);
            }
        }
}

// ---------------------------------------------------------------- launcher
extern "C" void kernel_launch(void* const* d_in, const int* in_sizes, int n_in,
                              void* d_out, int out_size, void* d_ws, size_t ws_size,
                              hipStream_t stream)
{
    const float* xA    = (const float*)d_in[0];
    const float* wk    = (const float*)d_in[1];
    const float* bk    = (const float*)d_in[2];
    const float* wv    = (const float*)d_in[3];
    const float* bv    = (const float*)d_in[4];
    const float* wq    = (const float*)d_in[5];
    const float* bq    = (const float*)d_in[6];
    const float* wwg   = (const float*)d_in[7];
    const float* bn1_g = (const float*)d_in[8];
    const float* bn1_b = (const float*)d_in[9];
    const float* bn1_m = (const float*)d_in[10];
    const float* bn1_v = (const float*)d_in[11];
    const float* wout  = (const float*)d_in[12];
    const float* bout  = (const float*)d_in[13];
    const float* bn2_g = (const float*)d_in[14];
    const float* bn2_b = (const float*)d_in[15];
    const float* bn2_m = (const float*)d_in[16];
    const float* bn2_v = (const float*)d_in[17];
    float* out = (float*)d_out;

    // ---- workspace layout (178 MB of 256 MiB) ----
    char* p = (char*)d_ws;
    bf16_t* Wb3    = (bf16_t*)p; p += 786432;      // wk|wv|wq bf16
    bf16_t* Wfb    = (bf16_t*)p; p += 262144;      // composed weight [512,256]
    float*  bfv    = (float*)p;  p += 2048;        // composed bias [512]
    bf16_t* xAt    = (bf16_t*)p;                   // [b,n,c] bf16 (dead after conv)
    bf16_t* avTb   = (bf16_t*)p; p += 16777216;    // ALIAS: [b,m,c] bf16 (8.4MB used)
    bf16_t* Kb     = (bf16_t*)p; p += 8388608;     // [b,c,n] (scaled in-place)
    bf16_t* Vt     = (bf16_t*)p; p += 8388608;     // [b,n,c]
    bf16_t* Qt     = (bf16_t*)p; p += 8388608;     // [b,n,c]
    float*  rowsum = (float*)p;  p += 65536;       // [b,n]
    bf16_t* Pt     = (bf16_t*)p; p += 134217728;   // [b,m,n] bf16, all batches

    prep_k<<<2112, 256, 0, stream>>>(wk, wv, wq, wwg, wout, bout,
                                     bn1_g, bn1_b, bn1_m, bn1_v,
                                     bn2_g, bn2_b, bn2_m, bn2_v,
                                     Wb3, Wfb, bfv, rowsum);
    txa_k<<<dim3(N_ / 32, C_ / 32, B_), dim3(32, 8), 0, stream>>>(xA, xAt);
    conv_mfma_k<<<dim3(N_ / 128, IC_ / 128, 3 * B_), 256, 0, stream>>>(
        Wb3, bk, bv, bq, xAt, Kb, Vt, Qt);

    s_mfma_t_k<<<dim3(N_ / 256, N_ / 256, B_), 512, 0, stream>>>(
        Qt, Vt, Pt, rowsum);
    kscale_k<<<2048, 256, 0, stream>>>(Kb, rowsum);
    av_mfma_k<<<dim3(N_ / 128, IC_ / 128, B_), 256, 0, stream>>>(Pt, Kb, avTb);

    out_mfma_k<<<dim3(N_ / 128, C_ / 128, B_), 256, 0, stream>>>(
        Wfb, bfv, avTb, xA, out);
}

// Round 5
// 287.545 us; speedup vs baseline: 1.0068x; 1.0068x over previous
//
#include <hip/hip_runtime.h>

// MFB fused non-local block, round 13.
// r12 post-mortem: 256^2 s-tile regressed (62.5->77us) because the BK=32
// read geometry 7x'd LDS bank conflicts (524K->3.67M) -- 64B rows put 16
// lanes on a 16-bank stride. Round 13: keep the 256^2 tile (economics were
// right) but BK=64 with the PROVEN 64-elem-row swizzle (row stride 128B =
// 32 banks, swz=l15&7 -> 2-way=free). 2 x 64KB buffers (128 KB LDS),
// issue-early/drain-late pipeline, NT=4. Everything else unchanged.

#define N_ 4096
#define C_ 512
#define IC_ 256
#define B_ 4

typedef __bf16 bf16_t;
typedef __bf16 bf16x8 __attribute__((ext_vector_type(8)));
typedef __bf16 bf16x4 __attribute__((ext_vector_type(4)));
typedef float f32x4 __attribute__((ext_vector_type(4)));

#define GLD(g, l) __builtin_amdgcn_global_load_lds(                              \
    (const __attribute__((address_space(1))) void*)(g),                          \
    (__attribute__((address_space(3))) void*)(l), 16, 0, 0)

// ---------------------------------------------------------------------------
// C[128x128] += A[m0.., K] * Bt[n0.., K]^T, bf16 in, fp32 acc. K mult of 64.
// 256 threads = 4 waves; wave (wr,wc) owns 64x64; acc[4][4] of f32x4.
// C/D layout (m89/m91): (i,j,reg) -> row wr+i*16+q*4+reg, col wc+j*16+l15.
// LDS: XOR-swizzled 64-elem rows; slot (row, c) holds global chunk c^(row&7).
// 2-buffer pipeline, smem = [2][lsA 8192 | lsB 8192] = 32768 elems (64 KB).
// ---------------------------------------------------------------------------
__device__ __forceinline__ void gemm_bt_128x128(
    const bf16_t* __restrict__ A, int lda,
    const bf16_t* __restrict__ Bt, int ldb,
    int K, int m0, int n0,
    bf16_t* smem, f32x4 acc[4][4])
{
    const int tid  = threadIdx.x;
    const int wave = tid >> 6, lane = tid & 63;
    const int wr = (wave >> 1) * 64, wc = (wave & 1) * 64;
    const int q = lane >> 4, l15 = lane & 15;
    const int srow = lane >> 3;                         // 0..7
    const int scol = (((lane & 7) ^ (srow & 7)) * 8);   // swizzled 8-elem chunk
    const int swz  = l15 & 7;

#define GB_STAGE(bi, kt)                                                        \
    do {                                                                        \
        bf16_t* lA = smem + (bi) * 16384;                                       \
        bf16_t* lB = lA + 8192;                                                 \
        _Pragma("unroll")                                                       \
        for (int c = 0; c < 4; ++c) {                                           \
            const int ch = wave * 4 + c;                                        \
            GLD(A  + (size_t)(m0 + ch * 8 + srow) * lda + (kt) + scol,          \
                lA + ch * 512);                                                 \
            GLD(Bt + (size_t)(n0 + ch * 8 + srow) * ldb + (kt) + scol,          \
                lB + ch * 512);                                                 \
        }                                                                       \
    } while (0)

    GB_STAGE(0, 0);
    asm volatile("s_waitcnt vmcnt(0)" ::: "memory");
    __builtin_amdgcn_s_barrier();
    asm volatile("" ::: "memory");

    const int nt = K / 64;
    for (int t = 0; t < nt; ++t) {
        const int cur = t & 1;
        if (t + 1 < nt) GB_STAGE(cur ^ 1, (t + 1) * 64);   // prefetch, in flight
        const bf16_t* lsA = smem + cur * 16384;
        const bf16_t* lsB = lsA + 8192;
#pragma unroll
        for (int ks = 0; ks < 2; ++ks) {
            bf16x8 af[4], bfr[4];
            const int co = ((ks * 4 + q) ^ swz) * 8;
#pragma unroll
            for (int i = 0; i < 4; ++i) {
                af[i]  = *(const bf16x8*)&lsA[(wr + i * 16 + l15) * 64 + co];
                bfr[i] = *(const bf16x8*)&lsB[(wc + i * 16 + l15) * 64 + co];
            }
#pragma unroll
            for (int i = 0; i < 4; ++i)
#pragma unroll
                for (int j = 0; j < 4; ++j)
                    acc[i][j] = __builtin_amdgcn_mfma_f32_16x16x32_bf16(
                        af[i], bfr[j], acc[i][j], 0, 0, 0);
        }
        // next tile's loads (issued above) land under the compute we just did
        asm volatile("s_waitcnt vmcnt(0)" ::: "memory");
        __builtin_amdgcn_s_barrier();
        asm volatile("" ::: "memory");
    }
#undef GB_STAGE
}

#define ACC_ZERO(acc)                                                           \
    _Pragma("unroll") for (int i = 0; i < 4; ++i)                               \
    _Pragma("unroll") for (int j = 0; j < 4; ++j)                               \
        acc[i][j] = f32x4{0.f, 0.f, 0.f, 0.f};

// ---- prep: castw3 (blocks 0..1535) | wf compose (1536..2047) | zero rowsum
__global__ __launch_bounds__(256) void prep_k(
    const float* __restrict__ wk, const float* __restrict__ wv,
    const float* __restrict__ wq,
    const float* __restrict__ wwg, const float* __restrict__ wout,
    const float* __restrict__ bout,
    const float* __restrict__ g1, const float* __restrict__ b1,
    const float* __restrict__ m1, const float* __restrict__ v1,
    const float* __restrict__ g2, const float* __restrict__ b2,
    const float* __restrict__ m2, const float* __restrict__ v2,
    bf16_t* __restrict__ Wb3, bf16_t* __restrict__ Wfb,
    float* __restrict__ bfv, float* __restrict__ rowsum)
{
    const int bid = blockIdx.x;
    __shared__ float ws[256];
    __shared__ float red[4];

    if (bid < 1536) {                 // cast wk|wv|wq to bf16
        const int i = bid * 256 + threadIdx.x;
        float v;
        if      (i < 131072) v = wk[i];
        else if (i < 262144) v = wv[i - 131072];
        else                 v = wq[i - 262144];
        Wb3[i] = (bf16_t)v;
    } else if (bid < 2048) {          // Wf = diag(s2) wout diag(s1) wwg + bias
        const int o = bid - 1536;     // 0..511
        const int j = threadIdx.x;    // 0..255
        const float s1 = g1[j] * rsqrtf(v1[j] + 1e-5f);
        const float wo = wout[o * 256 + j];
        ws[j] = wo * s1;
        float bp = wo * (b1[j] - m1[j] * s1);
#pragma unroll
        for (int off = 32; off > 0; off >>= 1) bp += __shfl_down(bp, off);
        if ((j & 63) == 0) red[j >> 6] = bp;
        __syncthreads();

        float acc = 0.f;
#pragma unroll 4
        for (int ic = 0; ic < 256; ++ic)
            acc += ws[ic] * wwg[ic * 256 + j];

        const float s2 = g2[o] * rsqrtf(v2[o] + 1e-5f);
        Wfb[o * 256 + j] = (bf16_t)(acc * s2);
        if (j == 0)
            bfv[o] = s2 * (red[0] + red[1] + red[2] + red[3] + bout[o])
                     - s2 * m2[o] + b2[o];
    } else {                          // zero rowsum[b][n] (16384 floats)
        rowsum[(bid - 2048) * 256 + threadIdx.x] = 0.f;
    }
}

// --------------------------------------------- xA [b,c,n] -> xAt [b,n,c] bf16
__global__ __launch_bounds__(256) void txa_k(
    const float* __restrict__ xA, bf16_t* __restrict__ xAt)
{
    __shared__ float t[32][33];
    const int b = blockIdx.z;
    const int n0 = blockIdx.x * 32, c0 = blockIdx.y * 32;
    const int tx = threadIdx.x, ty = threadIdx.y;
    const float* X = xA + (size_t)b * C_ * N_;
    bf16_t* Y = xAt + (size_t)b * N_ * C_;
#pragma unroll
    for (int r = 0; r < 4; ++r)
        t[ty + r * 8][tx] = X[(size_t)(c0 + ty + r * 8) * N_ + n0 + tx];
    __syncthreads();
#pragma unroll
    for (int r = 0; r < 4; ++r)
        Y[(size_t)(n0 + ty + r * 8) * C_ + c0 + tx] = (bf16_t)t[tx][ty + r * 8];
}

// ------------------------------------------ conv KVQ: W[o,c] * xAt[n,c]^T
__global__ __launch_bounds__(256) void conv_mfma_k(
    const bf16_t* __restrict__ Wb3,
    const float* __restrict__ bk, const float* __restrict__ bv,
    const float* __restrict__ bq, const bf16_t* __restrict__ xAt,
    bf16_t* __restrict__ Kb, bf16_t* __restrict__ Vt, bf16_t* __restrict__ Qt)
{
    __shared__ bf16_t smem[32768];
    const int which = blockIdx.z % 3, b = blockIdx.z / 3;
    const bf16_t* A = Wb3 + which * 131072;
    const float* bias = (which == 0) ? bk : (which == 1 ? bv : bq);
    const bf16_t* Bt = xAt + (size_t)b * N_ * C_;
    const int n0 = blockIdx.x * 128, m0 = blockIdx.y * 128;

    f32x4 acc[4][4];
    ACC_ZERO(acc);
    gemm_bt_128x128(A, C_, Bt, C_, C_, m0, n0, smem, acc);

    const int lane = threadIdx.x & 63, wave = threadIdx.x >> 6;
    const int q = lane >> 4, l15 = lane & 15;
    const int wr = (wave >> 1) * 64, wc = (wave & 1) * 64;

    if (which == 0) {                     // K: [c, n], n contiguous
        bf16_t* Y = Kb + (size_t)b * IC_ * N_;
#pragma unroll
        for (int i = 0; i < 4; ++i)
#pragma unroll
            for (int r = 0; r < 4; ++r) {
                const int o = m0 + wr + i * 16 + q * 4 + r;
                const float bo = bias[o];
#pragma unroll
                for (int j = 0; j < 4; ++j)
                    Y[(size_t)o * N_ + n0 + wc + j * 16 + l15] =
                        (bf16_t)(acc[i][j][r] + bo);
            }
    } else {                              // V/Q: [n, c], c contiguous
        bf16_t* Y = ((which == 1) ? Vt : Qt) + (size_t)b * N_ * IC_;
#pragma unroll
        for (int i = 0; i < 4; ++i) {
            const int ob = m0 + wr + i * 16 + q * 4;
            float bo[4];
#pragma unroll
            for (int r = 0; r < 4; ++r) bo[r] = bias[ob + r];
#pragma unroll
            for (int j = 0; j < 4; ++j) {
                const int n = n0 + wc + j * 16 + l15;
                bf16x4 v4;
#pragma unroll
                for (int r = 0; r < 4; ++r) v4[r] = (bf16_t)(acc[i][j][r] + bo[r]);
                *(bf16x4*)&Y[(size_t)n * IC_ + ob] = v4;
            }
        }
    }
}

// ---- S^T GEMM (batched), round 13: 256x256 tile, 512 threads = 8 waves
//      (2m x 4n, wave tile 128m x 64n, acc[8][4]). BK=64 with the PROVEN
//      64-elem-row swizzle (chunks of 8 rows x 128B, swz=l15&7). 2 x 64KB
//      LDS buffers, issue-early/drain-late pipeline, NT=4.
//      D[m,n]=Qt[m,:].Vt[n,:]; Pt[m,n]=exp(D) bf16; rowsum[n] += col sums.
//      Epilogue: two 128-col phases through a stride-136 LDS stage.
__global__ __launch_bounds__(512, 2) void s_mfma_t_k(
    const bf16_t* __restrict__ Qt, const bf16_t* __restrict__ Vt,
    bf16_t* __restrict__ Pt, float* __restrict__ rowsum)
{
    __shared__ bf16_t smem[65536];        // 2 x (A 16384 | B 16384) = 128 KB
    const int b  = blockIdx.z;
    const int n0 = blockIdx.x * 256;      // cols (n)
    const int m0 = blockIdx.y * 256;      // rows (m)
    const size_t NIC = (size_t)N_ * IC_;
    const bf16_t* Qb = Qt + (size_t)b * NIC;
    const bf16_t* Vb = Vt + (size_t)b * NIC;
    bf16_t* Pb = Pt + (size_t)b * N_ * N_;
    float* rs = rowsum + b * N_;

    const int tid  = threadIdx.x;         // 0..511
    const int wave = tid >> 6, lane = tid & 63;
    const int wr = wave >> 2;             // 0..1: m half (128 rows)
    const int wn = wave & 3;              // 0..3: n quarter (64 cols)
    const int q = lane >> 4, l15 = lane & 15;
    const int srow = lane >> 3;                         // 0..7
    const int scol = (((lane & 7) ^ (srow & 7)) * 8);   // swizzled 8-elem chunk
    const int swz  = l15 & 7;

    f32x4 acc[8][4];
#pragma unroll
    for (int i = 0; i < 8; ++i)
#pragma unroll
        for (int j = 0; j < 4; ++j) acc[i][j] = f32x4{0.f, 0.f, 0.f, 0.f};

    // per wave per tile: 4 A-chunks + 4 B-chunks (32 chunks each over 8 waves)
#define S_STAGE(bi, kt)                                                         \
    do {                                                                        \
        bf16_t* lA = smem + (bi) * 32768;                                       \
        bf16_t* lB = lA + 16384;                                                \
        _Pragma("unroll")                                                       \
        for (int c = 0; c < 4; ++c) {                                           \
            const int ch = wave * 4 + c;                                        \
            GLD(Qb + (size_t)(m0 + ch * 8 + srow) * IC_ + (kt) + scol,          \
                lA + ch * 512);                                                 \
            GLD(Vb + (size_t)(n0 + ch * 8 + srow) * IC_ + (kt) + scol,          \
                lB + ch * 512);                                                 \
        }                                                                       \
    } while (0)

    S_STAGE(0, 0);
    asm volatile("s_waitcnt vmcnt(0)" ::: "memory");
    __builtin_amdgcn_s_barrier();
    asm volatile("" ::: "memory");

    const int NT = IC_ / 64;              // 4 K-tiles
    for (int t = 0; t < NT; ++t) {
        const int cur = t & 1;
        if (t + 1 < NT) S_STAGE(cur ^ 1, (t + 1) * 64);   // prefetch, in flight
        const bf16_t* lsA = smem + cur * 32768;
        const bf16_t* lsB = lsA + 16384;
#pragma unroll
        for (int ks = 0; ks < 2; ++ks) {
            const int co = ((ks * 4 + q) ^ swz) * 8;
            bf16x8 af[8], bfv_[4];
#pragma unroll
            for (int i = 0; i < 8; ++i)
                af[i] = *(const bf16x8*)&lsA[(wr * 128 + i * 16 + l15) * 64 + co];
#pragma unroll
            for (int j = 0; j < 4; ++j)
                bfv_[j] = *(const bf16x8*)&lsB[(wn * 64 + j * 16 + l15) * 64 + co];
#pragma unroll
            for (int i = 0; i < 8; ++i)
#pragma unroll
                for (int j = 0; j < 4; ++j)
                    acc[i][j] = __builtin_amdgcn_mfma_f32_16x16x32_bf16(
                        af[i], bfv_[j], acc[i][j], 0, 0, 0);
        }
        asm volatile("s_waitcnt vmcnt(0)" ::: "memory");
        __builtin_amdgcn_s_barrier();
        asm volatile("" ::: "memory");
    }
#undef S_STAGE

    // ---- epilogue: exp + column sums + Pt store, two 128-col phases.
#pragma unroll
    for (int h = 0; h < 2; ++h) {
        if ((wn >> 1) == h) {
#pragma unroll
            for (int j = 0; j < 4; ++j) {
                float cs = 0.f;
#pragma unroll
                for (int i = 0; i < 8; ++i)
#pragma unroll
                    for (int r = 0; r < 4; ++r) {
                        const float e = __expf(acc[i][j][r]);
                        cs += e;
                        smem[(wr * 128 + i * 16 + q * 4 + r) * 136 +
                             (wn & 1) * 64 + j * 16 + l15] = (bf16_t)e;
                    }
                cs += __shfl_xor(cs, 16);
                cs += __shfl_xor(cs, 32);
                if (q == 0) atomicAdd(&rs[n0 + wn * 64 + j * 16 + l15], cs);
            }
        }
        __syncthreads();
        const int rr0 = tid >> 4;         // 0..31
        const int cc  = (tid & 15) * 8;   // 0..120
#pragma unroll
        for (int pp = 0; pp < 8; ++pp) {
            const int rr = rr0 + pp * 32;
            const bf16x8 v = *(const bf16x8*)&smem[rr * 136 + cc];
            *(bf16x8*)&Pb[(size_t)(m0 + rr) * N_ + n0 + h * 128 + cc] = v;
        }
        __syncthreads();
    }
}

// --------------- K'[b][c,n] = K[b][c,n] / rowsum[b][n], in-place (batched)
__global__ __launch_bounds__(256) void kscale_k(
    bf16_t* __restrict__ Kb, const float* __restrict__ rowsum)
{
    const size_t i8 = ((size_t)blockIdx.x * 256 + threadIdx.x) * 8;  // 2048 blocks
    const int n = (int)(i8 & (N_ - 1));
    const int b = (int)(i8 >> 20);                 // IC_*N_ = 2^20
    const float* rs = rowsum + b * N_;
    bf16x8 v = *(bf16x8*)&Kb[i8];
    const f32x4 r0 = *(const f32x4*)&rs[n];
    const f32x4 r1 = *(const f32x4*)&rs[n + 4];
#pragma unroll
    for (int k = 0; k < 4; ++k) {
        v[k]     = (bf16_t)((float)v[k]     / r0[k]);
        v[4 + k] = (bf16_t)((float)v[4 + k] / r1[k]);
    }
    *(bf16x8*)&Kb[i8] = v;
}

// ---- av GEMM (r10 structure, unchanged): 128m x 128c tile, grid (32,2,4) =
//      256 blocks. 3-buffer 2-deep pipeline with counted vmcnt(8).
__global__ __launch_bounds__(256) void av_mfma_k(
    const bf16_t* __restrict__ Pt, const bf16_t* __restrict__ Kb,
    bf16_t* __restrict__ avTb)
{
    // 3 buffers x (lsA 128x64 | lsB 128x64) = 3 x 32 KB = 96 KB.
    __shared__ bf16_t smem[3 * 16384];
    const int b  = blockIdx.z;
    const int m0 = blockIdx.x * 128;
    const int c0 = blockIdx.y * 128;
    const size_t NIC = (size_t)N_ * IC_;
    const bf16_t* Pb  = Pt + (size_t)b * N_ * N_ + (size_t)m0 * N_;
    const bf16_t* Kbb = Kb + (size_t)b * NIC + (size_t)c0 * N_;

    const int tid = threadIdx.x;
    const int wave = tid >> 6, lane = tid & 63;
    const int wr = (wave >> 1) * 64, wc = (wave & 1) * 64;
    const int q = lane >> 4, l15 = lane & 15;
    const int srow = lane >> 3;
    const int scol = (((lane & 7) ^ (srow & 7)) * 8);
    const int swz  = l15 & 7;

    f32x4 acc[4][4];
    ACC_ZERO(acc);

    // 8 GLDs per wave per tile: 4 A-chunks + 4 B-chunks (8 rows x 64 each).
#define AV_STAGE(buf, kt)                                                       \
    do {                                                                        \
        _Pragma("unroll")                                                       \
        for (int c = 0; c < 4; ++c) {                                           \
            const int ch = wave * 4 + c;                                        \
            GLD(Pb  + (size_t)(ch * 8 + srow) * N_ + (kt) + scol,               \
                (buf) + ch * 512);                                              \
            GLD(Kbb + (size_t)(ch * 8 + srow) * N_ + (kt) + scol,               \
                (buf) + 8192 + ch * 512);                                       \
        }                                                                       \
    } while (0)

    const int NT = N_ / 64;               // 64 K-tiles
    AV_STAGE(smem, 0);                    // prologue: 2 tiles in flight
    AV_STAGE(smem + 16384, 64);

    int bi_c = 0;                         // buffer holding tile t
    int bi_s = 2;                         // buffer to stage tile t+2 into
    for (int t = 0; t < NT; ++t) {
        if (t + 2 < NT) {
            // own tile-t loads done (8 newer, tile t+1, stay in flight)
            asm volatile("s_waitcnt vmcnt(8)" ::: "memory");
            __builtin_amdgcn_s_barrier();
            asm volatile("" ::: "memory");
            AV_STAGE(smem + bi_s * 16384, (t + 2) * 64);
        } else {
            asm volatile("s_waitcnt vmcnt(0)" ::: "memory");
            __builtin_amdgcn_s_barrier();
            asm volatile("" ::: "memory");
        }
        const bf16_t* lsA = smem + bi_c * 16384;
        const bf16_t* lsB = lsA + 8192;
#pragma unroll
        for (int ks = 0; ks < 2; ++ks) {
            const int co2 = ((ks * 4 + q) ^ swz) * 8;
            bf16x8 af[4], bfr[4];
#pragma unroll
            for (int i = 0; i < 4; ++i) {
                af[i]  = *(const bf16x8*)&lsA[(wr + i * 16 + l15) * 64 + co2];
                bfr[i] = *(const bf16x8*)&lsB[(wc + i * 16 + l15) * 64 + co2];
            }
#pragma unroll
            for (int i = 0; i < 4; ++i)
#pragma unroll
                for (int j = 0; j < 4; ++j)
                    acc[i][j] = __builtin_amdgcn_mfma_f32_16x16x32_bf16(
                        af[i], bfr[j], acc[i][j], 0, 0, 0);
        }
        bi_c = (bi_c == 2) ? 0 : bi_c + 1;
        bi_s = (bi_s == 2) ? 0 : bi_s + 1;
    }
#undef AV_STAGE
    __syncthreads();                      // all ds_reads of last tile done

    // epilogue: stage 128x128 bf16 (stride 136 elems = 272 B, 16B-aligned)
#pragma unroll
    for (int i = 0; i < 4; ++i)
#pragma unroll
        for (int j = 0; j < 4; ++j)
#pragma unroll
            for (int r = 0; r < 4; ++r)
                smem[(wr + i * 16 + q * 4 + r) * 136 + wc + j * 16 + l15] =
                    (bf16_t)acc[i][j][r];
    __syncthreads();

    bf16_t* Y = avTb + (size_t)b * NIC + (size_t)m0 * IC_ + c0;
    const int rr = tid >> 4;              // 0..15
    const int cc = (tid & 15) * 8;        // 0..120
#pragma unroll
    for (int p = 0; p < 8; ++p) {
        const int mm = rr + p * 16;
        const bf16x8 v = *(const bf16x8*)&smem[mm * 136 + cc];
        *(bf16x8*)&Y[(size_t)mm * IC_ + cc] = v;
    }
}

// ------------ final: out = relu( Wf . avT + bfv + xA ), fp32 out (batched)
__global__ __launch_bounds__(256) void out_mfma_k(
    const bf16_t* __restrict__ Wfb, const float* __restrict__ bfv,
    const bf16_t* __restrict__ avTb,
    const float* __restrict__ xA, float* __restrict__ out)
{
    __shared__ bf16_t smem[32768];
    const int b = blockIdx.z;
    const bf16_t* Bt = avTb + (size_t)b * N_ * IC_;
    const int n0 = blockIdx.x * 128, o0 = blockIdx.y * 128;

    f32x4 acc[4][4];
    ACC_ZERO(acc);
    gemm_bt_128x128(Wfb, IC_, Bt, IC_, IC_, o0, n0, smem, acc);

    const int lane = threadIdx.x & 63, wave = threadIdx.x >> 6;
    const int q = lane >> 4, l15 = lane & 15;
    const int wr = (wave >> 1) * 64, wc = (wave & 1) * 64;

#pragma unroll
    for (int i = 0; i < 4; ++i)
#pragma unroll
        for (int r = 0; r < 4; ++r) {
            const int o = o0 + wr + i * 16 + q * 4 + r;
            const float bo = bfv[o];
#pragma unroll
            for (int j = 0; j < 4; ++j) {
                const int n = n0 + wc + j * 16 + l15;
                const size_t idx = ((size_t)b * C_ + o) * N_ + n;
                out[idx] = fmaxf(acc[i][j][r] + bo + xA[idx], 0.f);
            }
        }
}

// ---------------------------------------------------------------- launcher
extern "C" void kernel_launch(void* const* d_in, const int* in_sizes, int n_in,
                              void* d_out, int out_size, void* d_ws, size_t ws_size,
                              hipStream_t stream)
{
    const float* xA    = (const float*)d_in[0];
    const float* wk    = (const float*)d_in[1];
    const float* bk    = (const float*)d_in[2];
    const float* wv    = (const float*)d_in[3];
    const float* bv    = (const float*)d_in[4];
    const float* wq    = (const float*)d_in[5];
    const float* bq    = (const float*)d_in[6];
    const float* wwg   = (const float*)d_in[7];
    const float* bn1_g = (const float*)d_in[8];
    const float* bn1_b = (const float*)d_in[9];
    const float* bn1_m = (const float*)d_in[10];
    const float* bn1_v = (const float*)d_in[11];
    const float* wout  = (const float*)d_in[12];
    const float* bout  = (const float*)d_in[13];
    const float* bn2_g = (const float*)d_in[14];
    const float* bn2_b = (const float*)d_in[15];
    const float* bn2_m = (const float*)d_in[16];
    const float* bn2_v = (const float*)d_in[17];
    float* out = (float*)d_out;

    // ---- workspace layout (178 MB of 256 MiB) ----
    char* p = (char*)d_ws;
    bf16_t* Wb3    = (bf16_t*)p; p += 786432;      // wk|wv|wq bf16
    bf16_t* Wfb    = (bf16_t*)p; p += 262144;      // composed weight [512,256]
    float*  bfv    = (float*)p;  p += 2048;        // composed bias [512]
    bf16_t* xAt    = (bf16_t*)p;                   // [b,n,c] bf16 (dead after conv)
    bf16_t* avTb   = (bf16_t*)p; p += 16777216;    // ALIAS: [b,m,c] bf16 (8.4MB used)
    bf16_t* Kb     = (bf16_t*)p; p += 8388608;     // [b,c,n] (scaled in-place)
    bf16_t* Vt     = (bf16_t*)p; p += 8388608;     // [b,n,c]
    bf16_t* Qt     = (bf16_t*)p; p += 8388608;     // [b,n,c]
    float*  rowsum = (float*)p;  p += 65536;       // [b,n]
    bf16_t* Pt     = (bf16_t*)p; p += 134217728;   // [b,m,n] bf16, all batches

    prep_k<<<2112, 256, 0, stream>>>(wk, wv, wq, wwg, wout, bout,
                                     bn1_g, bn1_b, bn1_m, bn1_v,
                                     bn2_g, bn2_b, bn2_m, bn2_v,
                                     Wb3, Wfb, bfv, rowsum);
    txa_k<<<dim3(N_ / 32, C_ / 32, B_), dim3(32, 8), 0, stream>>>(xA, xAt);
    conv_mfma_k<<<dim3(N_ / 128, IC_ / 128, 3 * B_), 256, 0, stream>>>(
        Wb3, bk, bv, bq, xAt, Kb, Vt, Qt);

    s_mfma_t_k<<<dim3(N_ / 256, N_ / 256, B_), 512, 0, stream>>>(
        Qt, Vt, Pt, rowsum);
    kscale_k<<<2048, 256, 0, stream>>>(Kb, rowsum);
    av_mfma_k<<<dim3(N_ / 128, IC_ / 128, B_), 256, 0, stream>>>(Pt, Kb, avTb);

    out_mfma_k<<<dim3(N_ / 128, C_ / 128, B_), 256, 0, stream>>>(
        Wfb, bfv, avTb, xA, out);
}

// Round 6
// 278.697 us; speedup vs baseline: 1.0388x; 1.0317x over previous
//
#include <hip/hip_runtime.h>

// MFB fused non-local block, round 14.
// r13 post-mortem: fixing bank conflicts (3.67M->524K) did NOT recover the
// 256^2 s-tile (75us vs 55.8 for r10's 128^2). Across 4 variants the perf
// correlate is blocks/CU (4 -> 2 -> 1 -> 1 maps to 55.8 -> 62.5 -> 77 -> 75):
// s is a mixed GEMM+exp+LDS-roundtrip+HBM-write kernel whose phases overlap
// only via co-resident blocks. Round 14: revert s to the r10 champion
// (128^2, 34.8 KB LDS, simple sync gemm, ~4 blocks/CU). conv/out keep the
// r11 pipelined gemm (it helped them); av keeps r10 structure.

#define N_ 4096
#define C_ 512
#define IC_ 256
#define B_ 4

typedef __bf16 bf16_t;
typedef __bf16 bf16x8 __attribute__((ext_vector_type(8)));
typedef __bf16 bf16x4 __attribute__((ext_vector_type(4)));
typedef float f32x4 __attribute__((ext_vector_type(4)));

#define GLD(g, l) __builtin_amdgcn_global_load_lds(                              \
    (const __attribute__((address_space(1))) void*)(g),                          \
    (__attribute__((address_space(3))) void*)(l), 16, 0, 0)

// ---------------------------------------------------------------------------
// Pipelined variant (conv/out): C[128x128] += A*Bt^T. 2-buffer, 64 KB,
// issue-early/drain-late. 256 thr = 4 waves, wave owns 64x64, acc[4][4].
// LDS: XOR-swizzled 64-elem rows; slot (row,c) holds global chunk c^(row&7).
// ---------------------------------------------------------------------------
__device__ __forceinline__ void gemm_bt_128x128(
    const bf16_t* __restrict__ A, int lda,
    const bf16_t* __restrict__ Bt, int ldb,
    int K, int m0, int n0,
    bf16_t* smem, f32x4 acc[4][4])
{
    const int tid  = threadIdx.x;
    const int wave = tid >> 6, lane = tid & 63;
    const int wr = (wave >> 1) * 64, wc = (wave & 1) * 64;
    const int q = lane >> 4, l15 = lane & 15;
    const int srow = lane >> 3;                         // 0..7
    const int scol = (((lane & 7) ^ (srow & 7)) * 8);   // swizzled 8-elem chunk
    const int swz  = l15 & 7;

#define GB_STAGE(bi, kt)                                                        \
    do {                                                                        \
        bf16_t* lA = smem + (bi) * 16384;                                       \
        bf16_t* lB = lA + 8192;                                                 \
        _Pragma("unroll")                                                       \
        for (int c = 0; c < 4; ++c) {                                           \
            const int ch = wave * 4 + c;                                        \
            GLD(A  + (size_t)(m0 + ch * 8 + srow) * lda + (kt) + scol,          \
                lA + ch * 512);                                                 \
            GLD(Bt + (size_t)(n0 + ch * 8 + srow) * ldb + (kt) + scol,          \
                lB + ch * 512);                                                 \
        }                                                                       \
    } while (0)

    GB_STAGE(0, 0);
    asm volatile("s_waitcnt vmcnt(0)" ::: "memory");
    __builtin_amdgcn_s_barrier();
    asm volatile("" ::: "memory");

    const int nt = K / 64;
    for (int t = 0; t < nt; ++t) {
        const int cur = t & 1;
        if (t + 1 < nt) GB_STAGE(cur ^ 1, (t + 1) * 64);   // prefetch, in flight
        const bf16_t* lsA = smem + cur * 16384;
        const bf16_t* lsB = lsA + 8192;
#pragma unroll
        for (int ks = 0; ks < 2; ++ks) {
            bf16x8 af[4], bfr[4];
            const int co = ((ks * 4 + q) ^ swz) * 8;
#pragma unroll
            for (int i = 0; i < 4; ++i) {
                af[i]  = *(const bf16x8*)&lsA[(wr + i * 16 + l15) * 64 + co];
                bfr[i] = *(const bf16x8*)&lsB[(wc + i * 16 + l15) * 64 + co];
            }
#pragma unroll
            for (int i = 0; i < 4; ++i)
#pragma unroll
                for (int j = 0; j < 4; ++j)
                    acc[i][j] = __builtin_amdgcn_mfma_f32_16x16x32_bf16(
                        af[i], bfr[j], acc[i][j], 0, 0, 0);
        }
        asm volatile("s_waitcnt vmcnt(0)" ::: "memory");
        __builtin_amdgcn_s_barrier();
        asm volatile("" ::: "memory");
    }
#undef GB_STAGE
}

// ---------------------------------------------------------------------------
// Sync variant (s): single 32 KB buffer, stage -> __syncthreads -> compute.
// Relies on multi-block co-residency (≈4 blocks/CU at 34.8 KB total LDS)
// for latency hiding -- measured fastest for the s workload (r10: 55.8us).
// ---------------------------------------------------------------------------
__device__ __forceinline__ void gemm_bt_128x128_sync(
    const bf16_t* __restrict__ A, int lda,
    const bf16_t* __restrict__ Bt, int ldb,
    int K, int m0, int n0,
    bf16_t* lsA, bf16_t* lsB, f32x4 acc[4][4])
{
    const int tid  = threadIdx.x;
    const int wave = tid >> 6, lane = tid & 63;
    const int wr = (wave >> 1) * 64, wc = (wave & 1) * 64;
    const int q = lane >> 4, l15 = lane & 15;
    const int srow = lane >> 3;
    const int scol = (((lane & 7) ^ (srow & 7)) * 8);
    const int swz  = l15 & 7;

    for (int kt = 0; kt < K; kt += 64) {
#pragma unroll
        for (int c = 0; c < 4; ++c) {
            const int ch = wave * 4 + c;
            GLD(A  + (size_t)(m0 + ch * 8 + srow) * lda + kt + scol, lsA + ch * 512);
            GLD(Bt + (size_t)(n0 + ch * 8 + srow) * ldb + kt + scol, lsB + ch * 512);
        }
        __syncthreads();
#pragma unroll
        for (int ks = 0; ks < 2; ++ks) {
            bf16x8 af[4], bfr[4];
            const int co = ((ks * 4 + q) ^ swz) * 8;
#pragma unroll
            for (int i = 0; i < 4; ++i) {
                af[i]  = *(const bf16x8*)&lsA[(wr + i * 16 + l15) * 64 + co];
                bfr[i] = *(const bf16x8*)&lsB[(wc + i * 16 + l15) * 64 + co];
            }
#pragma unroll
            for (int i = 0; i < 4; ++i)
#pragma unroll
                for (int j = 0; j < 4; ++j)
                    acc[i][j] = __builtin_amdgcn_mfma_f32_16x16x32_bf16(
                        af[i], bfr[j], acc[i][j], 0, 0, 0);
        }
        __syncthreads();
    }
}

#define ACC_ZERO(acc)                                                           \
    _Pragma("unroll") for (int i = 0; i < 4; ++i)                               \
    _Pragma("unroll") for (int j = 0; j < 4; ++j)                               \
        acc[i][j] = f32x4{0.f, 0.f, 0.f, 0.f};

// ---- prep: castw3 (blocks 0..1535) | wf compose (1536..2047) | zero rowsum
__global__ __launch_bounds__(256) void prep_k(
    const float* __restrict__ wk, const float* __restrict__ wv,
    const float* __restrict__ wq,
    const float* __restrict__ wwg, const float* __restrict__ wout,
    const float* __restrict__ bout,
    const float* __restrict__ g1, const float* __restrict__ b1,
    const float* __restrict__ m1, const float* __restrict__ v1,
    const float* __restrict__ g2, const float* __restrict__ b2,
    const float* __restrict__ m2, const float* __restrict__ v2,
    bf16_t* __restrict__ Wb3, bf16_t* __restrict__ Wfb,
    float* __restrict__ bfv, float* __restrict__ rowsum)
{
    const int bid = blockIdx.x;
    __shared__ float ws[256];
    __shared__ float red[4];

    if (bid < 1536) {                 // cast wk|wv|wq to bf16
        const int i = bid * 256 + threadIdx.x;
        float v;
        if      (i < 131072) v = wk[i];
        else if (i < 262144) v = wv[i - 131072];
        else                 v = wq[i - 262144];
        Wb3[i] = (bf16_t)v;
    } else if (bid < 2048) {          // Wf = diag(s2) wout diag(s1) wwg + bias
        const int o = bid - 1536;     // 0..511
        const int j = threadIdx.x;    // 0..255
        const float s1 = g1[j] * rsqrtf(v1[j] + 1e-5f);
        const float wo = wout[o * 256 + j];
        ws[j] = wo * s1;
        float bp = wo * (b1[j] - m1[j] * s1);
#pragma unroll
        for (int off = 32; off > 0; off >>= 1) bp += __shfl_down(bp, off);
        if ((j & 63) == 0) red[j >> 6] = bp;
        __syncthreads();

        float acc = 0.f;
#pragma unroll 4
        for (int ic = 0; ic < 256; ++ic)
            acc += ws[ic] * wwg[ic * 256 + j];

        const float s2 = g2[o] * rsqrtf(v2[o] + 1e-5f);
        Wfb[o * 256 + j] = (bf16_t)(acc * s2);
        if (j == 0)
            bfv[o] = s2 * (red[0] + red[1] + red[2] + red[3] + bout[o])
                     - s2 * m2[o] + b2[o];
    } else {                          // zero rowsum[b][n] (16384 floats)
        rowsum[(bid - 2048) * 256 + threadIdx.x] = 0.f;
    }
}

// --------------------------------------------- xA [b,c,n] -> xAt [b,n,c] bf16
__global__ __launch_bounds__(256) void txa_k(
    const float* __restrict__ xA, bf16_t* __restrict__ xAt)
{
    __shared__ float t[32][33];
    const int b = blockIdx.z;
    const int n0 = blockIdx.x * 32, c0 = blockIdx.y * 32;
    const int tx = threadIdx.x, ty = threadIdx.y;
    const float* X = xA + (size_t)b * C_ * N_;
    bf16_t* Y = xAt + (size_t)b * N_ * C_;
#pragma unroll
    for (int r = 0; r < 4; ++r)
        t[ty + r * 8][tx] = X[(size_t)(c0 + ty + r * 8) * N_ + n0 + tx];
    __syncthreads();
#pragma unroll
    for (int r = 0; r < 4; ++r)
        Y[(size_t)(n0 + ty + r * 8) * C_ + c0 + tx] = (bf16_t)t[tx][ty + r * 8];
}

// ------------------------------------------ conv KVQ: W[o,c] * xAt[n,c]^T
__global__ __launch_bounds__(256) void conv_mfma_k(
    const bf16_t* __restrict__ Wb3,
    const float* __restrict__ bk, const float* __restrict__ bv,
    const float* __restrict__ bq, const bf16_t* __restrict__ xAt,
    bf16_t* __restrict__ Kb, bf16_t* __restrict__ Vt, bf16_t* __restrict__ Qt)
{
    __shared__ bf16_t smem[32768];
    const int which = blockIdx.z % 3, b = blockIdx.z / 3;
    const bf16_t* A = Wb3 + which * 131072;
    const float* bias = (which == 0) ? bk : (which == 1 ? bv : bq);
    const bf16_t* Bt = xAt + (size_t)b * N_ * C_;
    const int n0 = blockIdx.x * 128, m0 = blockIdx.y * 128;

    f32x4 acc[4][4];
    ACC_ZERO(acc);
    gemm_bt_128x128(A, C_, Bt, C_, C_, m0, n0, smem, acc);

    const int lane = threadIdx.x & 63, wave = threadIdx.x >> 6;
    const int q = lane >> 4, l15 = lane & 15;
    const int wr = (wave >> 1) * 64, wc = (wave & 1) * 64;

    if (which == 0) {                     // K: [c, n], n contiguous
        bf16_t* Y = Kb + (size_t)b * IC_ * N_;
#pragma unroll
        for (int i = 0; i < 4; ++i)
#pragma unroll
            for (int r = 0; r < 4; ++r) {
                const int o = m0 + wr + i * 16 + q * 4 + r;
                const float bo = bias[o];
#pragma unroll
                for (int j = 0; j < 4; ++j)
                    Y[(size_t)o * N_ + n0 + wc + j * 16 + l15] =
                        (bf16_t)(acc[i][j][r] + bo);
            }
    } else {                              // V/Q: [n, c], c contiguous
        bf16_t* Y = ((which == 1) ? Vt : Qt) + (size_t)b * N_ * IC_;
#pragma unroll
        for (int i = 0; i < 4; ++i) {
            const int ob = m0 + wr + i * 16 + q * 4;
            float bo[4];
#pragma unroll
            for (int r = 0; r < 4; ++r) bo[r] = bias[ob + r];
#pragma unroll
            for (int j = 0; j < 4; ++j) {
                const int n = n0 + wc + j * 16 + l15;
                bf16x4 v4;
#pragma unroll
                for (int r = 0; r < 4; ++r) v4[r] = (bf16_t)(acc[i][j][r] + bo[r]);
                *(bf16x4*)&Y[(size_t)n * IC_ + ob] = v4;
            }
        }
    }
}

// ---- S^T GEMM (batched), r10 champion: 128^2 tile, 256 thr, 34.8 KB LDS
//      (~4 blocks/CU). D[m,n]=Qt[m,:].Vt[n,:]; Pt[b][m,n]=exp(D) bf16;
//      rowsum[b][n] += column sums. LDS stage (stride 136) -> b128 stores.
__global__ __launch_bounds__(256) void s_mfma_t_k(
    const bf16_t* __restrict__ Qt, const bf16_t* __restrict__ Vt,
    bf16_t* __restrict__ Pt, float* __restrict__ rowsum)
{
    __shared__ bf16_t smem[17408];
    const int b  = blockIdx.z;
    const int n0 = blockIdx.x * 128;      // cols (n)
    const int m0 = blockIdx.y * 128;      // rows (m)
    const size_t NIC = (size_t)N_ * IC_;
    const bf16_t* Qb = Qt + (size_t)b * NIC;
    const bf16_t* Vb = Vt + (size_t)b * NIC;
    bf16_t* Pb = Pt + (size_t)b * N_ * N_;
    float* rs = rowsum + b * N_;

    f32x4 acc[4][4];
    ACC_ZERO(acc);
    gemm_bt_128x128_sync(Qb, IC_, Vb, IC_, IC_, m0, n0, smem, smem + 8192, acc);

    const int tid = threadIdx.x;
    const int lane = tid & 63, wave = tid >> 6;
    const int q = lane >> 4, l15 = lane & 15;
    const int wr = (wave >> 1) * 64, wc = (wave & 1) * 64;

#pragma unroll
    for (int j = 0; j < 4; ++j) {
        float cs = 0.f;
#pragma unroll
        for (int i = 0; i < 4; ++i)
#pragma unroll
            for (int r = 0; r < 4; ++r) {
                const float e = __expf(acc[i][j][r]);
                cs += e;
                smem[(wr + i * 16 + q * 4 + r) * 136 + wc + j * 16 + l15] = (bf16_t)e;
            }
        cs += __shfl_xor(cs, 16);
        cs += __shfl_xor(cs, 32);
        if (q == 0) atomicAdd(&rs[n0 + wc + j * 16 + l15], cs);
    }
    __syncthreads();

    const int rr = tid >> 4;              // 0..15
    const int cc = (tid & 15) * 8;        // 0..120
#pragma unroll
    for (int p = 0; p < 8; ++p) {
        const int mm = rr + p * 16;
        const bf16x8 v = *(const bf16x8*)&smem[mm * 136 + cc];
        *(bf16x8*)&Pb[(size_t)(m0 + mm) * N_ + n0 + cc] = v;
    }
}

// --------------- K'[b][c,n] = K[b][c,n] / rowsum[b][n], in-place (batched)
__global__ __launch_bounds__(256) void kscale_k(
    bf16_t* __restrict__ Kb, const float* __restrict__ rowsum)
{
    const size_t i8 = ((size_t)blockIdx.x * 256 + threadIdx.x) * 8;  // 2048 blocks
    const int n = (int)(i8 & (N_ - 1));
    const int b = (int)(i8 >> 20);                 // IC_*N_ = 2^20
    const float* rs = rowsum + b * N_;
    bf16x8 v = *(bf16x8*)&Kb[i8];
    const f32x4 r0 = *(const f32x4*)&rs[n];
    const f32x4 r1 = *(const f32x4*)&rs[n + 4];
#pragma unroll
    for (int k = 0; k < 4; ++k) {
        v[k]     = (bf16_t)((float)v[k]     / r0[k]);
        v[4 + k] = (bf16_t)((float)v[4 + k] / r1[k]);
    }
    *(bf16x8*)&Kb[i8] = v;
}

// ---- av GEMM (r10 structure, unchanged): 128m x 128c tile, grid (32,2,4) =
//      256 blocks. 3-buffer 2-deep pipeline with counted vmcnt(8).
__global__ __launch_bounds__(256) void av_mfma_k(
    const bf16_t* __restrict__ Pt, const bf16_t* __restrict__ Kb,
    bf16_t* __restrict__ avTb)
{
    // 3 buffers x (lsA 128x64 | lsB 128x64) = 3 x 32 KB = 96 KB.
    __shared__ bf16_t smem[3 * 16384];
    const int b  = blockIdx.z;
    const int m0 = blockIdx.x * 128;
    const int c0 = blockIdx.y * 128;
    const size_t NIC = (size_t)N_ * IC_;
    const bf16_t* Pb  = Pt + (size_t)b * N_ * N_ + (size_t)m0 * N_;
    const bf16_t* Kbb = Kb + (size_t)b * NIC + (size_t)c0 * N_;

    const int tid = threadIdx.x;
    const int wave = tid >> 6, lane = tid & 63;
    const int wr = (wave >> 1) * 64, wc = (wave & 1) * 64;
    const int q = lane >> 4, l15 = lane & 15;
    const int srow = lane >> 3;
    const int scol = (((lane & 7) ^ (srow & 7)) * 8);
    const int swz  = l15 & 7;

    f32x4 acc[4][4];
    ACC_ZERO(acc);

    // 8 GLDs per wave per tile: 4 A-chunks + 4 B-chunks (8 rows x 64 each).
#define AV_STAGE(buf, kt)                                                       \
    do {                                                                        \
        _Pragma("unroll")                                                       \
        for (int c = 0; c < 4; ++c) {                                           \
            const int ch = wave * 4 + c;                                        \
            GLD(Pb  + (size_t)(ch * 8 + srow) * N_ + (kt) + scol,               \
                (buf) + ch * 512);                                              \
            GLD(Kbb + (size_t)(ch * 8 + srow) * N_ + (kt) + scol,               \
                (buf) + 8192 + ch * 512);                                       \
        }                                                                       \
    } while (0)

    const int NT = N_ / 64;               // 64 K-tiles
    AV_STAGE(smem, 0);                    // prologue: 2 tiles in flight
    AV_STAGE(smem + 16384, 64);

    int bi_c = 0;                         // buffer holding tile t
    int bi_s = 2;                         // buffer to stage tile t+2 into
    for (int t = 0; t < NT; ++t) {
        if (t + 2 < NT) {
            // own tile-t loads done (8 newer, tile t+1, stay in flight)
            asm volatile("s_waitcnt vmcnt(8)" ::: "memory");
            __builtin_amdgcn_s_barrier();
            asm volatile("" ::: "memory");
            AV_STAGE(smem + bi_s * 16384, (t + 2) * 64);
        } else {
            asm volatile("s_waitcnt vmcnt(0)" ::: "memory");
            __builtin_amdgcn_s_barrier();
            asm volatile("" ::: "memory");
        }
        const bf16_t* lsA = smem + bi_c * 16384;
        const bf16_t* lsB = lsA + 8192;
#pragma unroll
        for (int ks = 0; ks < 2; ++ks) {
            const int co2 = ((ks * 4 + q) ^ swz) * 8;
            bf16x8 af[4], bfr[4];
#pragma unroll
            for (int i = 0; i < 4; ++i) {
                af[i]  = *(const bf16x8*)&lsA[(wr + i * 16 + l15) * 64 + co2];
                bfr[i] = *(const bf16x8*)&lsB[(wc + i * 16 + l15) * 64 + co2];
            }
#pragma unroll
            for (int i = 0; i < 4; ++i)
#pragma unroll
                for (int j = 0; j < 4; ++j)
                    acc[i][j] = __builtin_amdgcn_mfma_f32_16x16x32_bf16(
                        af[i], bfr[j], acc[i][j], 0, 0, 0);
        }
        bi_c = (bi_c == 2) ? 0 : bi_c + 1;
        bi_s = (bi_s == 2) ? 0 : bi_s + 1;
    }
#undef AV_STAGE
    __syncthreads();                      // all ds_reads of last tile done

    // epilogue: stage 128x128 bf16 (stride 136 elems = 272 B, 16B-aligned)
#pragma unroll
    for (int i = 0; i < 4; ++i)
#pragma unroll
        for (int j = 0; j < 4; ++j)
#pragma unroll
            for (int r = 0; r < 4; ++r)
                smem[(wr + i * 16 + q * 4 + r) * 136 + wc + j * 16 + l15] =
                    (bf16_t)acc[i][j][r];
    __syncthreads();

    bf16_t* Y = avTb + (size_t)b * NIC + (size_t)m0 * IC_ + c0;
    const int rr = tid >> 4;              // 0..15
    const int cc = (tid & 15) * 8;        // 0..120
#pragma unroll
    for (int p = 0; p < 8; ++p) {
        const int mm = rr + p * 16;
        const bf16x8 v = *(const bf16x8*)&smem[mm * 136 + cc];
        *(bf16x8*)&Y[(size_t)mm * IC_ + cc] = v;
    }
}

// ------------ final: out = relu( Wf . avT + bfv + xA ), fp32 out (batched)
__global__ __launch_bounds__(256) void out_mfma_k(
    const bf16_t* __restrict__ Wfb, const float* __restrict__ bfv,
    const bf16_t* __restrict__ avTb,
    const float* __restrict__ xA, float* __restrict__ out)
{
    __shared__ bf16_t smem[32768];
    const int b = blockIdx.z;
    const bf16_t* Bt = avTb + (size_t)b * N_ * IC_;
    const int n0 = blockIdx.x * 128, o0 = blockIdx.y * 128;

    f32x4 acc[4][4];
    ACC_ZERO(acc);
    gemm_bt_128x128(Wfb, IC_, Bt, IC_, IC_, o0, n0, smem, acc);

    const int lane = threadIdx.x & 63, wave = threadIdx.x >> 6;
    const int q = lane >> 4, l15 = lane & 15;
    const int wr = (wave >> 1) * 64, wc = (wave & 1) * 64;

#pragma unroll
    for (int i = 0; i < 4; ++i)
#pragma unroll
        for (int r = 0; r < 4; ++r) {
            const int o = o0 + wr + i * 16 + q * 4 + r;
            const float bo = bfv[o];
#pragma unroll
            for (int j = 0; j < 4; ++j) {
                const int n = n0 + wc + j * 16 + l15;
                const size_t idx = ((size_t)b * C_ + o) * N_ + n;
                out[idx] = fmaxf(acc[i][j][r] + bo + xA[idx], 0.f);
            }
        }
}

// ---------------------------------------------------------------- launcher
extern "C" void kernel_launch(void* const* d_in, const int* in_sizes, int n_in,
                              void* d_out, int out_size, void* d_ws, size_t ws_size,
                              hipStream_t stream)
{
    const float* xA    = (const float*)d_in[0];
    const float* wk    = (const float*)d_in[1];
    const float* bk    = (const float*)d_in[2];
    const float* wv    = (const float*)d_in[3];
    const float* bv    = (const float*)d_in[4];
    const float* wq    = (const float*)d_in[5];
    const float* bq    = (const float*)d_in[6];
    const float* wwg   = (const float*)d_in[7];
    const float* bn1_g = (const float*)d_in[8];
    const float* bn1_b = (const float*)d_in[9];
    const float* bn1_m = (const float*)d_in[10];
    const float* bn1_v = (const float*)d_in[11];
    const float* wout  = (const float*)d_in[12];
    const float* bout  = (const float*)d_in[13];
    const float* bn2_g = (const float*)d_in[14];
    const float* bn2_b = (const float*)d_in[15];
    const float* bn2_m = (const float*)d_in[16];
    const float* bn2_v = (const float*)d_in[17];
    float* out = (float*)d_out;

    // ---- workspace layout (178 MB of 256 MiB) ----
    char* p = (char*)d_ws;
    bf16_t* Wb3    = (bf16_t*)p; p += 786432;      // wk|wv|wq bf16
    bf16_t* Wfb    = (bf16_t*)p; p += 262144;      // composed weight [512,256]
    float*  bfv    = (float*)p;  p += 2048;        // composed bias [512]
    bf16_t* xAt    = (bf16_t*)p;                   // [b,n,c] bf16 (dead after conv)
    bf16_t* avTb   = (bf16_t*)p; p += 16777216;    // ALIAS: [b,m,c] bf16 (8.4MB used)
    bf16_t* Kb     = (bf16_t*)p; p += 8388608;     // [b,c,n] (scaled in-place)
    bf16_t* Vt     = (bf16_t*)p; p += 8388608;     // [b,n,c]
    bf16_t* Qt     = (bf16_t*)p; p += 8388608;     // [b,n,c]
    float*  rowsum = (float*)p;  p += 65536;       // [b,n]
    bf16_t* Pt     = (bf16_t*)p; p += 134217728;   // [b,m,n] bf16, all batches

    prep_k<<<2112, 256, 0, stream>>>(wk, wv, wq, wwg, wout, bout,
                                     bn1_g, bn1_b, bn1_m, bn1_v,
                                     bn2_g, bn2_b, bn2_m, bn2_v,
                                     Wb3, Wfb, bfv, rowsum);
    txa_k<<<dim3(N_ / 32, C_ / 32, B_), dim3(32, 8), 0, stream>>>(xA, xAt);
    conv_mfma_k<<<dim3(N_ / 128, IC_ / 128, 3 * B_), 256, 0, stream>>>(
        Wb3, bk, bv, bq, xAt, Kb, Vt, Qt);

    s_mfma_t_k<<<dim3(N_ / 128, N_ / 128, B_), 256, 0, stream>>>(
        Qt, Vt, Pt, rowsum);
    kscale_k<<<2048, 256, 0, stream>>>(Kb, rowsum);
    av_mfma_k<<<dim3(N_ / 128, IC_ / 128, B_), 256, 0, stream>>>(Pt, Kb, avTb);

    out_mfma_k<<<dim3(N_ / 128, C_ / 128, B_), 256, 0, stream>>>(
        Wfb, bfv, avTb, xA, out);
}

// Round 7
// 274.915 us; speedup vs baseline: 1.0531x; 1.0138x over previous
//
#include <hip/hip_runtime.h>

// MFB fused non-local block, round 15.
// r14 matrix across 5 s-variants: co-residency dominates; pipelining that
// costs residency loses. Untested cell: pipelined AND 4 blocks/CU. BK=32
// makes the dbuf 2x16KB=32KB < the 34.8KB epilogue stage (LDS high-water
// unchanged -> same ~4 blocks/CU) with issue-early/drain-late ordering.
// r12's BK=32 bank-conflict trap avoided via paired-row layout: LDS row
// (128B) holds TWO m-rows, slot ps=(p*4+c)^(r&7) -> 2-way/free per phase;
// staging dest linear, permutation on the global source (rule 21).
// Only s changes; conv/out keep r11 pipelined gemm; av keeps r10.

#define N_ 4096
#define C_ 512
#define IC_ 256
#define B_ 4

typedef __bf16 bf16_t;
typedef __bf16 bf16x8 __attribute__((ext_vector_type(8)));
typedef __bf16 bf16x4 __attribute__((ext_vector_type(4)));
typedef float f32x4 __attribute__((ext_vector_type(4)));

#define GLD(g, l) __builtin_amdgcn_global_load_lds(                              \
    (const __attribute__((address_space(1))) void*)(g),                          \
    (__attribute__((address_space(3))) void*)(l), 16, 0, 0)

// ---------------------------------------------------------------------------
// Pipelined variant (conv/out): C[128x128] += A*Bt^T. 2-buffer, 64 KB,
// issue-early/drain-late. 256 thr = 4 waves, wave owns 64x64, acc[4][4].
// LDS: XOR-swizzled 64-elem rows; slot (row,c) holds global chunk c^(row&7).
// ---------------------------------------------------------------------------
__device__ __forceinline__ void gemm_bt_128x128(
    const bf16_t* __restrict__ A, int lda,
    const bf16_t* __restrict__ Bt, int ldb,
    int K, int m0, int n0,
    bf16_t* smem, f32x4 acc[4][4])
{
    const int tid  = threadIdx.x;
    const int wave = tid >> 6, lane = tid & 63;
    const int wr = (wave >> 1) * 64, wc = (wave & 1) * 64;
    const int q = lane >> 4, l15 = lane & 15;
    const int srow = lane >> 3;                         // 0..7
    const int scol = (((lane & 7) ^ (srow & 7)) * 8);   // swizzled 8-elem chunk
    const int swz  = l15 & 7;

#define GB_STAGE(bi, kt)                                                        \
    do {                                                                        \
        bf16_t* lA = smem + (bi) * 16384;                                       \
        bf16_t* lB = lA + 8192;                                                 \
        _Pragma("unroll")                                                       \
        for (int c = 0; c < 4; ++c) {                                           \
            const int ch = wave * 4 + c;                                        \
            GLD(A  + (size_t)(m0 + ch * 8 + srow) * lda + (kt) + scol,          \
                lA + ch * 512);                                                 \
            GLD(Bt + (size_t)(n0 + ch * 8 + srow) * ldb + (kt) + scol,          \
                lB + ch * 512);                                                 \
        }                                                                       \
    } while (0)

    GB_STAGE(0, 0);
    asm volatile("s_waitcnt vmcnt(0)" ::: "memory");
    __builtin_amdgcn_s_barrier();
    asm volatile("" ::: "memory");

    const int nt = K / 64;
    for (int t = 0; t < nt; ++t) {
        const int cur = t & 1;
        if (t + 1 < nt) GB_STAGE(cur ^ 1, (t + 1) * 64);   // prefetch, in flight
        const bf16_t* lsA = smem + cur * 16384;
        const bf16_t* lsB = lsA + 8192;
#pragma unroll
        for (int ks = 0; ks < 2; ++ks) {
            bf16x8 af[4], bfr[4];
            const int co = ((ks * 4 + q) ^ swz) * 8;
#pragma unroll
            for (int i = 0; i < 4; ++i) {
                af[i]  = *(const bf16x8*)&lsA[(wr + i * 16 + l15) * 64 + co];
                bfr[i] = *(const bf16x8*)&lsB[(wc + i * 16 + l15) * 64 + co];
            }
#pragma unroll
            for (int i = 0; i < 4; ++i)
#pragma unroll
                for (int j = 0; j < 4; ++j)
                    acc[i][j] = __builtin_amdgcn_mfma_f32_16x16x32_bf16(
                        af[i], bfr[j], acc[i][j], 0, 0, 0);
        }
        asm volatile("s_waitcnt vmcnt(0)" ::: "memory");
        __builtin_amdgcn_s_barrier();
        asm volatile("" ::: "memory");
    }
#undef GB_STAGE
}

#define ACC_ZERO(acc)                                                           \
    _Pragma("unroll") for (int i = 0; i < 4; ++i)                               \
    _Pragma("unroll") for (int j = 0; j < 4; ++j)                               \
        acc[i][j] = f32x4{0.f, 0.f, 0.f, 0.f};

// ---- prep: castw3 (blocks 0..1535) | wf compose (1536..2047) | zero rowsum
__global__ __launch_bounds__(256) void prep_k(
    const float* __restrict__ wk, const float* __restrict__ wv,
    const float* __restrict__ wq,
    const float* __restrict__ wwg, const float* __restrict__ wout,
    const float* __restrict__ bout,
    const float* __restrict__ g1, const float* __restrict__ b1,
    const float* __restrict__ m1, const float* __restrict__ v1,
    const float* __restrict__ g2, const float* __restrict__ b2,
    const float* __restrict__ m2, const float* __restrict__ v2,
    bf16_t* __restrict__ Wb3, bf16_t* __restrict__ Wfb,
    float* __restrict__ bfv, float* __restrict__ rowsum)
{
    const int bid = blockIdx.x;
    __shared__ float ws[256];
    __shared__ float red[4];

    if (bid < 1536) {                 // cast wk|wv|wq to bf16
        const int i = bid * 256 + threadIdx.x;
        float v;
        if      (i < 131072) v = wk[i];
        else if (i < 262144) v = wv[i - 131072];
        else                 v = wq[i - 262144];
        Wb3[i] = (bf16_t)v;
    } else if (bid < 2048) {          // Wf = diag(s2) wout diag(s1) wwg + bias
        const int o = bid - 1536;     // 0..511
        const int j = threadIdx.x;    // 0..255
        const float s1 = g1[j] * rsqrtf(v1[j] + 1e-5f);
        const float wo = wout[o * 256 + j];
        ws[j] = wo * s1;
        float bp = wo * (b1[j] - m1[j] * s1);
#pragma unroll
        for (int off = 32; off > 0; off >>= 1) bp += __shfl_down(bp, off);
        if ((j & 63) == 0) red[j >> 6] = bp;
        __syncthreads();

        float acc = 0.f;
#pragma unroll 4
        for (int ic = 0; ic < 256; ++ic)
            acc += ws[ic] * wwg[ic * 256 + j];

        const float s2 = g2[o] * rsqrtf(v2[o] + 1e-5f);
        Wfb[o * 256 + j] = (bf16_t)(acc * s2);
        if (j == 0)
            bfv[o] = s2 * (red[0] + red[1] + red[2] + red[3] + bout[o])
                     - s2 * m2[o] + b2[o];
    } else {                          // zero rowsum[b][n] (16384 floats)
        rowsum[(bid - 2048) * 256 + threadIdx.x] = 0.f;
    }
}

// --------------------------------------------- xA [b,c,n] -> xAt [b,n,c] bf16
__global__ __launch_bounds__(256) void txa_k(
    const float* __restrict__ xA, bf16_t* __restrict__ xAt)
{
    __shared__ float t[32][33];
    const int b = blockIdx.z;
    const int n0 = blockIdx.x * 32, c0 = blockIdx.y * 32;
    const int tx = threadIdx.x, ty = threadIdx.y;
    const float* X = xA + (size_t)b * C_ * N_;
    bf16_t* Y = xAt + (size_t)b * N_ * C_;
#pragma unroll
    for (int r = 0; r < 4; ++r)
        t[ty + r * 8][tx] = X[(size_t)(c0 + ty + r * 8) * N_ + n0 + tx];
    __syncthreads();
#pragma unroll
    for (int r = 0; r < 4; ++r)
        Y[(size_t)(n0 + ty + r * 8) * C_ + c0 + tx] = (bf16_t)t[tx][ty + r * 8];
}

// ------------------------------------------ conv KVQ: W[o,c] * xAt[n,c]^T
__global__ __launch_bounds__(256) void conv_mfma_k(
    const bf16_t* __restrict__ Wb3,
    const float* __restrict__ bk, const float* __restrict__ bv,
    const float* __restrict__ bq, const bf16_t* __restrict__ xAt,
    bf16_t* __restrict__ Kb, bf16_t* __restrict__ Vt, bf16_t* __restrict__ Qt)
{
    __shared__ bf16_t smem[32768];
    const int which = blockIdx.z % 3, b = blockIdx.z / 3;
    const bf16_t* A = Wb3 + which * 131072;
    const float* bias = (which == 0) ? bk : (which == 1 ? bv : bq);
    const bf16_t* Bt = xAt + (size_t)b * N_ * C_;
    const int n0 = blockIdx.x * 128, m0 = blockIdx.y * 128;

    f32x4 acc[4][4];
    ACC_ZERO(acc);
    gemm_bt_128x128(A, C_, Bt, C_, C_, m0, n0, smem, acc);

    const int lane = threadIdx.x & 63, wave = threadIdx.x >> 6;
    const int q = lane >> 4, l15 = lane & 15;
    const int wr = (wave >> 1) * 64, wc = (wave & 1) * 64;

    if (which == 0) {                     // K: [c, n], n contiguous
        bf16_t* Y = Kb + (size_t)b * IC_ * N_;
#pragma unroll
        for (int i = 0; i < 4; ++i)
#pragma unroll
            for (int r = 0; r < 4; ++r) {
                const int o = m0 + wr + i * 16 + q * 4 + r;
                const float bo = bias[o];
#pragma unroll
                for (int j = 0; j < 4; ++j)
                    Y[(size_t)o * N_ + n0 + wc + j * 16 + l15] =
                        (bf16_t)(acc[i][j][r] + bo);
            }
    } else {                              // V/Q: [n, c], c contiguous
        bf16_t* Y = ((which == 1) ? Vt : Qt) + (size_t)b * N_ * IC_;
#pragma unroll
        for (int i = 0; i < 4; ++i) {
            const int ob = m0 + wr + i * 16 + q * 4;
            float bo[4];
#pragma unroll
            for (int r = 0; r < 4; ++r) bo[r] = bias[ob + r];
#pragma unroll
            for (int j = 0; j < 4; ++j) {
                const int n = n0 + wc + j * 16 + l15;
                bf16x4 v4;
#pragma unroll
                for (int r = 0; r < 4; ++r) v4[r] = (bf16_t)(acc[i][j][r] + bo[r]);
                *(bf16x4*)&Y[(size_t)n * IC_ + ob] = v4;
            }
        }
    }
}

// ---- S^T GEMM (batched), round 15: 128^2 tile, BK=32 paired-row layout,
//      2x16KB dbuf (LDS high-water stays 34.8KB -> ~4 blocks/CU) with
//      issue-early/drain-late pipeline, NT=8.
//      LDS row r (128B) holds m-rows {2r,2r+1}; slot ps=(p*4+c)^(r&7).
//      Staging dest is linear (buf + R0*64 + lane*8); the permutation is
//      applied to the global source address. Read: 2-way/free per phase.
//      D[m,n]=Qt[m,:].Vt[n,:]; Pt[b][m,n]=exp(D) bf16; rowsum[b][n]+=colsums.
__global__ __launch_bounds__(256) void s_mfma_t_k(
    const bf16_t* __restrict__ Qt, const bf16_t* __restrict__ Vt,
    bf16_t* __restrict__ Pt, float* __restrict__ rowsum)
{
    __shared__ bf16_t smem[17408];        // bufs use 16384; epilogue uses 17408
    const int b  = blockIdx.z;
    const int n0 = blockIdx.x * 128;      // cols (n)
    const int m0 = blockIdx.y * 128;      // rows (m)
    const size_t NIC = (size_t)N_ * IC_;
    const bf16_t* Qb = Qt + (size_t)b * NIC;
    const bf16_t* Vb = Vt + (size_t)b * NIC;
    bf16_t* Pb = Pt + (size_t)b * N_ * N_;
    float* rs = rowsum + b * N_;

    const int tid = threadIdx.x;
    const int wave = tid >> 6, lane = tid & 63;
    const int q = lane >> 4, l15 = lane & 15;
    const int wr = (wave >> 1) * 64, wc = (wave & 1) * 64;

    // staging lane constants: inst covers 8 LDS rows; r&7 == lane>>3
    const int rowoff = lane >> 3;               // 0..7
    const int sA = (lane & 7) ^ rowoff;         // logical slot
    const int pA = sA >> 2, cA = (sA & 3) * 8;  // m-parity, K-chunk offset
    // read lane constants: r = rbase + (l15>>1), r&7 == l15>>1
    const int rl = l15 >> 1;
    const int slot_q = ((((l15 & 1) * 4 + q)) ^ rl) * 8;

    f32x4 acc[4][4];
    ACC_ZERO(acc);

    // per wave per tile: 2 insts x (A,B); each inst = 8 LDS rows = 1 KB
#define S_STAGE(bi, kt)                                                         \
    do {                                                                        \
        bf16_t* lA = smem + (bi) * 8192;                                        \
        bf16_t* lB = lA + 4096;                                                 \
        _Pragma("unroll")                                                       \
        for (int e = 0; e < 2; ++e) {                                           \
            const int R0 = wave * 16 + e * 8;                                   \
            const int gr = 2 * (R0 + rowoff) + pA;                              \
            GLD(Qb + (size_t)(m0 + gr) * IC_ + (kt) + cA,                       \
                lA + R0 * 64 + lane * 8);                                       \
            GLD(Vb + (size_t)(n0 + gr) * IC_ + (kt) + cA,                       \
                lB + R0 * 64 + lane * 8);                                       \
        }                                                                       \
    } while (0)

    S_STAGE(0, 0);
    asm volatile("s_waitcnt vmcnt(0)" ::: "memory");
    __builtin_amdgcn_s_barrier();
    asm volatile("" ::: "memory");

    const int NT = IC_ / 32;              // 8 K-tiles
    for (int t = 0; t < NT; ++t) {
        const int cur = t & 1;
        if (t + 1 < NT) S_STAGE(cur ^ 1, (t + 1) * 32);   // prefetch, in flight
        const bf16_t* lsA = smem + cur * 8192;
        const bf16_t* lsB = lsA + 4096;
        bf16x8 af[4], bfr[4];
#pragma unroll
        for (int i = 0; i < 4; ++i) {
            af[i]  = *(const bf16x8*)&lsA[((wr >> 1) + i * 8 + rl) * 64 + slot_q];
            bfr[i] = *(const bf16x8*)&lsB[((wc >> 1) + i * 8 + rl) * 64 + slot_q];
        }
#pragma unroll
        for (int i = 0; i < 4; ++i)
#pragma unroll
            for (int j = 0; j < 4; ++j)
                acc[i][j] = __builtin_amdgcn_mfma_f32_16x16x32_bf16(
                    af[i], bfr[j], acc[i][j], 0, 0, 0);
        asm volatile("s_waitcnt vmcnt(0)" ::: "memory");
        __builtin_amdgcn_s_barrier();
        asm volatile("" ::: "memory");
    }
#undef S_STAGE

    // ---- epilogue: exp + column sums + Pt store (r10 pattern, unchanged)
#pragma unroll
    for (int j = 0; j < 4; ++j) {
        float cs = 0.f;
#pragma unroll
        for (int i = 0; i < 4; ++i)
#pragma unroll
            for (int r = 0; r < 4; ++r) {
                const float e = __expf(acc[i][j][r]);
                cs += e;
                smem[(wr + i * 16 + q * 4 + r) * 136 + wc + j * 16 + l15] = (bf16_t)e;
            }
        cs += __shfl_xor(cs, 16);
        cs += __shfl_xor(cs, 32);
        if (q == 0) atomicAdd(&rs[n0 + wc + j * 16 + l15], cs);
    }
    __syncthreads();

    const int rr = tid >> 4;              // 0..15
    const int cc = (tid & 15) * 8;        // 0..120
#pragma unroll
    for (int p = 0; p < 8; ++p) {
        const int mm = rr + p * 16;
        const bf16x8 v = *(const bf16x8*)&smem[mm * 136 + cc];
        *(bf16x8*)&Pb[(size_t)(m0 + mm) * N_ + n0 + cc] = v;
    }
}

// --------------- K'[b][c,n] = K[b][c,n] / rowsum[b][n], in-place (batched)
__global__ __launch_bounds__(256) void kscale_k(
    bf16_t* __restrict__ Kb, const float* __restrict__ rowsum)
{
    const size_t i8 = ((size_t)blockIdx.x * 256 + threadIdx.x) * 8;  // 2048 blocks
    const int n = (int)(i8 & (N_ - 1));
    const int b = (int)(i8 >> 20);                 // IC_*N_ = 2^20
    const float* rs = rowsum + b * N_;
    bf16x8 v = *(bf16x8*)&Kb[i8];
    const f32x4 r0 = *(const f32x4*)&rs[n];
    const f32x4 r1 = *(const f32x4*)&rs[n + 4];
#pragma unroll
    for (int k = 0; k < 4; ++k) {
        v[k]     = (bf16_t)((float)v[k]     / r0[k]);
        v[4 + k] = (bf16_t)((float)v[4 + k] / r1[k]);
    }
    *(bf16x8*)&Kb[i8] = v;
}

// ---- av GEMM (r10 structure, unchanged): 128m x 128c tile, grid (32,2,4) =
//      256 blocks. 3-buffer 2-deep pipeline with counted vmcnt(8).
__global__ __launch_bounds__(256) void av_mfma_k(
    const bf16_t* __restrict__ Pt, const bf16_t* __restrict__ Kb,
    bf16_t* __restrict__ avTb)
{
    // 3 buffers x (lsA 128x64 | lsB 128x64) = 3 x 32 KB = 96 KB.
    __shared__ bf16_t smem[3 * 16384];
    const int b  = blockIdx.z;
    const int m0 = blockIdx.x * 128;
    const int c0 = blockIdx.y * 128;
    const size_t NIC = (size_t)N_ * IC_;
    const bf16_t* Pb  = Pt + (size_t)b * N_ * N_ + (size_t)m0 * N_;
    const bf16_t* Kbb = Kb + (size_t)b * NIC + (size_t)c0 * N_;

    const int tid = threadIdx.x;
    const int wave = tid >> 6, lane = tid & 63;
    const int wr = (wave >> 1) * 64, wc = (wave & 1) * 64;
    const int q = lane >> 4, l15 = lane & 15;
    const int srow = lane >> 3;
    const int scol = (((lane & 7) ^ (srow & 7)) * 8);
    const int swz  = l15 & 7;

    f32x4 acc[4][4];
    ACC_ZERO(acc);

    // 8 GLDs per wave per tile: 4 A-chunks + 4 B-chunks (8 rows x 64 each).
#define AV_STAGE(buf, kt)                                                       \
    do {                                                                        \
        _Pragma("unroll")                                                       \
        for (int c = 0; c < 4; ++c) {                                           \
            const int ch = wave * 4 + c;                                        \
            GLD(Pb  + (size_t)(ch * 8 + srow) * N_ + (kt) + scol,               \
                (buf) + ch * 512);                                              \
            GLD(Kbb + (size_t)(ch * 8 + srow) * N_ + (kt) + scol,               \
                (buf) + 8192 + ch * 512);                                       \
        }                                                                       \
    } while (0)

    const int NT = N_ / 64;               // 64 K-tiles
    AV_STAGE(smem, 0);                    // prologue: 2 tiles in flight
    AV_STAGE(smem + 16384, 64);

    int bi_c = 0;                         // buffer holding tile t
    int bi_s = 2;                         // buffer to stage tile t+2 into
    for (int t = 0; t < NT; ++t) {
        if (t + 2 < NT) {
            // own tile-t loads done (8 newer, tile t+1, stay in flight)
            asm volatile("s_waitcnt vmcnt(8)" ::: "memory");
            __builtin_amdgcn_s_barrier();
            asm volatile("" ::: "memory");
            AV_STAGE(smem + bi_s * 16384, (t + 2) * 64);
        } else {
            asm volatile("s_waitcnt vmcnt(0)" ::: "memory");
            __builtin_amdgcn_s_barrier();
            asm volatile("" ::: "memory");
        }
        const bf16_t* lsA = smem + bi_c * 16384;
        const bf16_t* lsB = lsA + 8192;
#pragma unroll
        for (int ks = 0; ks < 2; ++ks) {
            const int co2 = ((ks * 4 + q) ^ swz) * 8;
            bf16x8 af[4], bfr[4];
#pragma unroll
            for (int i = 0; i < 4; ++i) {
                af[i]  = *(const bf16x8*)&lsA[(wr + i * 16 + l15) * 64 + co2];
                bfr[i] = *(const bf16x8*)&lsB[(wc + i * 16 + l15) * 64 + co2];
            }
#pragma unroll
            for (int i = 0; i < 4; ++i)
#pragma unroll
                for (int j = 0; j < 4; ++j)
                    acc[i][j] = __builtin_amdgcn_mfma_f32_16x16x32_bf16(
                        af[i], bfr[j], acc[i][j], 0, 0, 0);
        }
        bi_c = (bi_c == 2) ? 0 : bi_c + 1;
        bi_s = (bi_s == 2) ? 0 : bi_s + 1;
    }
#undef AV_STAGE
    __syncthreads();                      // all ds_reads of last tile done

    // epilogue: stage 128x128 bf16 (stride 136 elems = 272 B, 16B-aligned)
#pragma unroll
    for (int i = 0; i < 4; ++i)
#pragma unroll
        for (int j = 0; j < 4; ++j)
#pragma unroll
            for (int r = 0; r < 4; ++r)
                smem[(wr + i * 16 + q * 4 + r) * 136 + wc + j * 16 + l15] =
                    (bf16_t)acc[i][j][r];
    __syncthreads();

    bf16_t* Y = avTb + (size_t)b * NIC + (size_t)m0 * IC_ + c0;
    const int rr = tid >> 4;              // 0..15
    const int cc = (tid & 15) * 8;        // 0..120
#pragma unroll
    for (int p = 0; p < 8; ++p) {
        const int mm = rr + p * 16;
        const bf16x8 v = *(const bf16x8*)&smem[mm * 136 + cc];
        *(bf16x8*)&Y[(size_t)mm * IC_ + cc] = v;
    }
}

// ------------ final: out = relu( Wf . avT + bfv + xA ), fp32 out (batched)
__global__ __launch_bounds__(256) void out_mfma_k(
    const bf16_t* __restrict__ Wfb, const float* __restrict__ bfv,
    const bf16_t* __restrict__ avTb,
    const float* __restrict__ xA, float* __restrict__ out)
{
    __shared__ bf16_t smem[32768];
    const int b = blockIdx.z;
    const bf16_t* Bt = avTb + (size_t)b * N_ * IC_;
    const int n0 = blockIdx.x * 128, o0 = blockIdx.y * 128;

    f32x4 acc[4][4];
    ACC_ZERO(acc);
    gemm_bt_128x128(Wfb, IC_, Bt, IC_, IC_, o0, n0, smem, acc);

    const int lane = threadIdx.x & 63, wave = threadIdx.x >> 6;
    const int q = lane >> 4, l15 = lane & 15;
    const int wr = (wave >> 1) * 64, wc = (wave & 1) * 64;

#pragma unroll
    for (int i = 0; i < 4; ++i)
#pragma unroll
        for (int r = 0; r < 4; ++r) {
            const int o = o0 + wr + i * 16 + q * 4 + r;
            const float bo = bfv[o];
#pragma unroll
            for (int j = 0; j < 4; ++j) {
                const int n = n0 + wc + j * 16 + l15;
                const size_t idx = ((size_t)b * C_ + o) * N_ + n;
                out[idx] = fmaxf(acc[i][j][r] + bo + xA[idx], 0.f);
            }
        }
}

// ---------------------------------------------------------------- launcher
extern "C" void kernel_launch(void* const* d_in, const int* in_sizes, int n_in,
                              void* d_out, int out_size, void* d_ws, size_t ws_size,
                              hipStream_t stream)
{
    const float* xA    = (const float*)d_in[0];
    const float* wk    = (const float*)d_in[1];
    const float* bk    = (const float*)d_in[2];
    const float* wv    = (const float*)d_in[3];
    const float* bv    = (const float*)d_in[4];
    const float* wq    = (const float*)d_in[5];
    const float* bq    = (const float*)d_in[6];
    const float* wwg   = (const float*)d_in[7];
    const float* bn1_g = (const float*)d_in[8];
    const float* bn1_b = (const float*)d_in[9];
    const float* bn1_m = (const float*)d_in[10];
    const float* bn1_v = (const float*)d_in[11];
    const float* wout  = (const float*)d_in[12];
    const float* bout  = (const float*)d_in[13];
    const float* bn2_g = (const float*)d_in[14];
    const float* bn2_b = (const float*)d_in[15];
    const float* bn2_m = (const float*)d_in[16];
    const float* bn2_v = (const float*)d_in[17];
    float* out = (float*)d_out;

    // ---- workspace layout (178 MB of 256 MiB) ----
    char* p = (char*)d_ws;
    bf16_t* Wb3    = (bf16_t*)p; p += 786432;      // wk|wv|wq bf16
    bf16_t* Wfb    = (bf16_t*)p; p += 262144;      // composed weight [512,256]
    float*  bfv    = (float*)p;  p += 2048;        // composed bias [512]
    bf16_t* xAt    = (bf16_t*)p;                   // [b,n,c] bf16 (dead after conv)
    bf16_t* avTb   = (bf16_t*)p; p += 16777216;    // ALIAS: [b,m,c] bf16 (8.4MB used)
    bf16_t* Kb     = (bf16_t*)p; p += 8388608;     // [b,c,n] (scaled in-place)
    bf16_t* Vt     = (bf16_t*)p; p += 8388608;     // [b,n,c]
    bf16_t* Qt     = (bf16_t*)p; p += 8388608;     // [b,n,c]
    float*  rowsum = (float*)p;  p += 65536;       // [b,n]
    bf16_t* Pt     = (bf16_t*)p; p += 134217728;   // [b,m,n] bf16, all batches

    prep_k<<<2112, 256, 0, stream>>>(wk, wv, wq, wwg, wout, bout,
                                     bn1_g, bn1_b, bn1_m, bn1_v,
                                     bn2_g, bn2_b, bn2_m, bn2_v,
                                     Wb3, Wfb, bfv, rowsum);
    txa_k<<<dim3(N_ / 32, C_ / 32, B_), dim3(32, 8), 0, stream>>>(xA, xAt);
    conv_mfma_k<<<dim3(N_ / 128, IC_ / 128, 3 * B_), 256, 0, stream>>>(
        Wb3, bk, bv, bq, xAt, Kb, Vt, Qt);

    s_mfma_t_k<<<dim3(N_ / 128, N_ / 128, B_), 256, 0, stream>>>(
        Qt, Vt, Pt, rowsum);
    kscale_k<<<2048, 256, 0, stream>>>(Kb, rowsum);
    av_mfma_k<<<dim3(N_ / 128, IC_ / 128, B_), 256, 0, stream>>>(Pt, Kb, avTb);

    out_mfma_k<<<dim3(N_ / 128, C_ / 128, B_), 256, 0, stream>>>(
        Wfb, bfv, avTb, xA, out);
}